// Round 10
// baseline (164.458 us; speedup 1.0000x reference)
//
#include <hip/hip_runtime.h>
#include <hip/hip_bf16.h>
#include <cstddef>
#include <cstdint>

// SpatialPatchMoE on MI355X (gfx950).
// x[2,64,8,128,128] f32 -> 512 patches x 8 l-slices; router top-2/8;
// per expert: dwconv(1,7,7) -> LN(8,8) -> pw 64->128 -> silu*gate -> pw 64->64;
// out = x + sum_k w_k * expert_k.  Pointwise matmuls = bf16 MFMA 16x16x32.
//
// k_main: 512 threads = 8 waves; wave wv owns conv row wv and MFMA row-tile
// (wv>>1) x px-half (wv&1).  NO __launch_bounds__ min-waves (rounds 4-6: any
// min-waves cap makes the allocator spill 300-500 MB of scratch).
// Round 10: conv uses P/S aligned/shifted pair scheme (24 pk_fma + 10 movs
// per row); weights staged [c][dy][8] -> 2x ds_read_b128 per row.
//
// ws layout (bytes):
//   partial_l : f32 [n][l][c]       @ 0         (1048576)
//   dwT       : f32 [e][c][7][8]    @ 1048576   (114688)
//   sel_i     : int[2*512]          @ 1163264   (4096)
//   sel_w     : f32[2*512]          @ 1167360   (4096)
//   wInBf     : bf16 [e][128][64]   @ 1171456   (131072)
//   wOutBf    : bf16 [e][64][64]    @ 1302528   (65536)
//   xr        : f32 [n*8+l][c][px]  @ 1368064   (67108864)   (repack path)

typedef __attribute__((ext_vector_type(8))) short short8;
typedef __attribute__((ext_vector_type(4))) float f32x4;
typedef __attribute__((ext_vector_type(2))) float f32x2;

#define REPACK_NEED 68476928ull

__device__ __forceinline__ unsigned short f2bf(float f) {
  return __builtin_bit_cast(unsigned short, __float2bfloat16(f));
}

__device__ __forceinline__ float wave_sum64(float v) {
#pragma unroll
  for (int m = 32; m > 0; m >>= 1) v += __shfl_xor(v, m, 64);
  return v;
}

// ---------------- preprocess: dw -> padded [e][c][7][8] + pw weights -> bf16
__global__ void k_pre(const float* __restrict__ dw,
                      const float* __restrict__ pwin,
                      const float* __restrict__ pwout,
                      float* __restrict__ dwT,
                      unsigned short* __restrict__ wIn,
                      unsigned short* __restrict__ wOut) {
  int idx = blockIdx.x * 256 + threadIdx.x;
  if (idx < 28672) {
    int e = idx / 3584;
    int r = idx - e * 3584;
    int c = r / 56;
    int q = r - c * 56;
    int dy = q >> 3, dx = q & 7;
    dwT[idx] = (dx < 7) ? dw[(e * 64 + c) * 49 + dy * 7 + dx] : 0.f;
  } else if (idx < 94208) {
    int i = idx - 28672;
    wIn[i] = f2bf(pwin[i]);
  } else if (idx < 126976) {
    int i = idx - 94208;
    wOut[i] = f2bf(pwout[i]);
  }
}

// ---------------- fallback patch sums (only when ws too small for repack)
__global__ __launch_bounds__(256) void k_sum(const float* __restrict__ x,
                                             float* __restrict__ partial_l) {
  __shared__ float red[256 * 17];
  int t = threadIdx.x, bid = blockIdx.x;
  int b = bid >> 8, c = (bid >> 2) & 63, lp = bid & 3;
  const float4* x4 = (const float4*)x + ((size_t)((b * 64 + c) * 8) + lp * 2) * 4096;
#pragma unroll 1
  for (int l2 = 0; l2 < 2; ++l2) {
    float acc[16];
#pragma unroll
    for (int k = 0; k < 16; ++k) acc[k] = 0.f;
#pragma unroll
    for (int k = 0; k < 16; ++k) {
      float4 v = x4[l2 * 4096 + k * 256 + t];
      acc[k] += v.x + v.y + v.z + v.w;
    }
    int pcol = (t & 31) >> 1;
    int slot = ((t & 1) << 3) | (t >> 5);
    __syncthreads();
#pragma unroll
    for (int k = 0; k < 16; ++k) red[(k * 16 + pcol) * 17 + slot] = acc[k];
    __syncthreads();
    float s = 0.f;
#pragma unroll
    for (int j = 0; j < 16; ++j) s += red[t * 17 + j];
    partial_l[((size_t)(b * 256 + t)) * 512 + (lp * 2 + l2) * 64 + c] = s;
  }
}

// ---------------- repack x -> patch-major xr[(n*8+l)][c][px], fused patch sums
__global__ __launch_bounds__(256) void k_repack(const float* __restrict__ x,
                                                float* __restrict__ xr,
                                                float* __restrict__ partial_l) {
  __shared__ __align__(16) float lt[8 * 1060];
  int t = threadIdx.x, bid = blockIdx.x;
  int ct = bid & 7, hh = (bid >> 3) & 15, l = (bid >> 7) & 7, b = bid >> 10;
  int c0 = ct * 8;
  const float4* x4 = (const float4*)x;
  float4* xr4 = (float4*)xr;
  int y = t >> 5, xq = t & 31;
#pragma unroll
  for (int i = 0; i < 8; ++i) {
    size_t src = ((size_t)((b * 64 + c0 + i) * 8 + l) << 12) +
                 (size_t)(hh * 8 + y) * 32 + xq;
    float4 v = x4[src];
    *(float4*)(lt + i * 1060 + y * 132 + xq * 4) = v;
  }
  __syncthreads();
  int cc = (t >> 4) & 7, ihalf = t >> 7, pxq = t & 15;
  int py = pxq >> 1, xcol = pxq & 1;
#pragma unroll
  for (int iw = 0; iw < 8; ++iw) {
    int ww = ihalf * 8 + iw;
    float4 v = *(const float4*)(lt + cc * 1060 + py * 132 + ww * 8 + xcol * 4);
    int n = b * 256 + hh * 16 + ww;
    xr4[((size_t)(n * 8 + l) << 10) + (c0 + cc) * 16 + pxq] = v;
    float s = v.x + v.y + v.z + v.w;
#pragma unroll
    for (int m = 1; m < 16; m <<= 1) s += __shfl_xor(s, m, 64);
    if (pxq == 0) partial_l[(size_t)(n * 8 + l) * 64 + c0 + cc] = s;
  }
}

// ---------------- router
__global__ void k_router(const float* __restrict__ partial_l,
                         const float* __restrict__ rw, const float* __restrict__ rb,
                         int* __restrict__ sel_i, float* __restrict__ sel_w) {
  int n = blockIdx.x;
  int lane = threadIdx.x;
  float s = 0.f;
#pragma unroll
  for (int l = 0; l < 8; ++l)
    s += partial_l[(size_t)n * 512 + l * 64 + lane];
  float rin = s * (1.f / 512.f);
  float lg[8];
#pragma unroll
  for (int e = 0; e < 8; ++e) {
    float v = rin * rw[e * 64 + lane];
    lg[e] = wave_sum64(v) + rb[e];
  }
  int e0 = 0; float v0 = lg[0];
#pragma unroll
  for (int e = 1; e < 8; ++e) if (lg[e] > v0) { v0 = lg[e]; e0 = e; }
  int e1 = -1; float v1 = -1e30f;
#pragma unroll
  for (int e = 0; e < 8; ++e) if (e != e0 && lg[e] > v1) { v1 = lg[e]; e1 = e; }
  if (lane == 0) {
    float w1 = __expf(v1 - v0);
    float z = 1.f + w1;
    sel_i[2 * n] = e0; sel_i[2 * n + 1] = e1;
    sel_w[2 * n] = 1.f / z; sel_w[2 * n + 1] = w1 / z;
  }
}

// ---------------- main: one block per (patch n, depth l); 8 waves of 64
template <bool REPACK>
__global__ __launch_bounds__(512) void k_main(
    const float* __restrict__ x, const float* __restrict__ xr,
    const float* __restrict__ dwT, const float* __restrict__ dwb,
    const float* __restrict__ lnw, const float* __restrict__ lnb,
    const float* __restrict__ pwin_b, const float* __restrict__ pwout_b,
    const unsigned short* __restrict__ wInBf,
    const unsigned short* __restrict__ wOutBf,
    const int* __restrict__ sel_i, const float* __restrict__ sel_w,
    float* __restrict__ out) {
  // carve: wsdw f32[c][7][8] @0 (14336) | hbf u16[64*72] @14336 (9216)
  //        | h3bf u16[64*72] @23552 (9216) | lnred f32x2[8][64] @32768 (4096)
  //        | xs f32[64*68] @36864 (17408)  => 54272 B (3 blocks/CU: 162816<=163840)
  __shared__ __align__(16) char smem[54272];
  float* wsdw          = (float*)smem;
  unsigned short* hbf  = (unsigned short*)(smem + 14336);
  unsigned short* h3bf = (unsigned short*)(smem + 23552);
  float* lnred         = (float*)(smem + 32768);
  float* xs            = (float*)(smem + 36864);
  float* eb            = (float*)smem;  // epilogue alias over wsdw+hbf[0:3072)

  const int t = threadIdx.x;
  const int lane = t & 63;
  const int wv = __builtin_amdgcn_readfirstlane(t >> 6);  // 0..7
  const int wi = wv >> 1;      // MFMA row-tile index 0..3
  const int jh = wv & 1;       // px-half 0..1
  const int r15 = lane & 15, r4 = lane >> 4;
  const int bidx = blockIdx.x;
  const int n = bidx >> 3, l = bidx & 7;
  const int b = n >> 8, p = n & 255;
  const int hh = p >> 4, ww = p & 15;
  const size_t obase = (size_t)b * 8388608 + (size_t)l * 16384 +
                       (size_t)hh * 1024 + (size_t)ww * 8;

  // ---- stage x slice -> xs [c][px], stride 68, XOR row swizzle r^((c>>3)&7)
#pragma unroll
  for (int it = 0; it < 2; ++it) {
    int g = it * 512 + t;
    int c = g >> 4, q = g & 15;
    float4 v;
    if constexpr (REPACK)
      v = ((const float4*)xr)[(size_t)bidx * 1024 + g];
    else
      v = *(const float4*)(x + obase + (size_t)c * 131072 + (q >> 1) * 128 + (q & 1) * 4);
    int rs = (q >> 1) ^ ((c >> 3) & 7);
    *(float4*)(xs + c * 68 + rs * 8 + (q & 1) * 4) = v;
  }
  // no barrier here: syncW below covers xs too

  float oacc[8];
#pragma unroll
  for (int i = 0; i < 8; ++i) oacc[i] = 0.f;

#pragma unroll 1
  for (int k = 0; k < 2; ++k) {
    const int e = __builtin_amdgcn_readfirstlane(sel_i[2 * n + k]);
    const float we = sel_w[2 * n + k];

    // ---- stage expert dw weights into LDS: [c][7][8] = 896 float4
    {
      const float4* src = (const float4*)(dwT + e * 3584);
      float4* dst = (float4*)wsdw;
      dst[t] = src[t];
      if (t < 384) dst[512 + t] = src[512 + t];
    }
    __syncthreads();  // syncW: wsdw + xs ready (k=0); guards hbf/h3bf reuse (k=1)

    // ---- depthwise conv: lane = channel; wave wv owns output row wv (8 px)
    //      P/S pair scheme: even-dx taps use aligned pairs (free from b128),
    //      odd-shift pairs built once per row; zero-operand FMAs elided.
    f32x2 hv2[4];
    {
      const float bias = dwb[e * 64 + lane];
#pragma unroll
      for (int j = 0; j < 4; ++j) hv2[j] = f32x2{bias, bias};
    }
    {
      const float* rowbase = xs + lane * 68;
      const int rc = (lane >> 3) & 7;
      const float* wbase = wsdw + lane * 56;
      const int y0 = wv;
      const int rlo = (y0 - 3 < 0) ? 0 : y0 - 3;
      const int rhi = (y0 + 3 > 7) ? 7 : y0 + 3;
      for (int r = rlo; r <= rhi; ++r) {
        const float* xrow = rowbase + 8 * (r ^ rc);
        float4 a0 = *(const float4*)xrow;
        float4 a1 = *(const float4*)(xrow + 4);
        const float* wrow = wbase + (r - y0 + 3) * 8;
        float4 w03 = *(const float4*)wrow;
        float4 w47 = *(const float4*)(wrow + 4);   // .w is pad
        f32x2 P2 = {a0.x, a0.y}, P3 = {a0.z, a0.w};
        f32x2 P4 = {a1.x, a1.y}, P5 = {a1.z, a1.w};
        f32x2 S1 = {0.f, a0.x}, S2 = {a0.y, a0.z}, S3 = {a0.w, a1.x};
        f32x2 S4 = {a1.y, a1.z}, S5 = {a1.w, 0.f};
#define FMA2(J, PAIR, W) hv2[J] = __builtin_elementwise_fma(PAIR, f32x2{W, W}, hv2[J])
        // dx=0 (S_{j}):   j=0 zero
        FMA2(1, S1, w03.x); FMA2(2, S2, w03.x); FMA2(3, S3, w03.x);
        // dx=1 (P_{j+1}): j=0 zero
        FMA2(1, P2, w03.y); FMA2(2, P3, w03.y); FMA2(3, P4, w03.y);
        // dx=2 (S_{j+1}):
        FMA2(0, S1, w03.z); FMA2(1, S2, w03.z); FMA2(2, S3, w03.z); FMA2(3, S4, w03.z);
        // dx=3 (P_{j+2}):
        FMA2(0, P2, w03.w); FMA2(1, P3, w03.w); FMA2(2, P4, w03.w); FMA2(3, P5, w03.w);
        // dx=4 (S_{j+2}):
        FMA2(0, S2, w47.x); FMA2(1, S3, w47.x); FMA2(2, S4, w47.x); FMA2(3, S5, w47.x);
        // dx=5 (P_{j+3}): j=3 zero
        FMA2(0, P3, w47.y); FMA2(1, P4, w47.y); FMA2(2, P5, w47.y);
        // dx=6 (S_{j+3}): j=3 zero
        FMA2(0, S3, w47.z); FMA2(1, S4, w47.z); FMA2(2, S5, w47.z);
#undef FMA2
      }
    }

    // ---- LayerNorm over 64 pixels per channel (8 wave-partials, f32x2 packed)
    f32x2 ps2 = f32x2{0.f, 0.f}, pq2 = f32x2{0.f, 0.f};
#pragma unroll
    for (int j = 0; j < 4; ++j) {
      ps2 += hv2[j];
      pq2 = __builtin_elementwise_fma(hv2[j], hv2[j], pq2);
    }
    *(f32x2*)(lnred + (wv * 64 + lane) * 2) = f32x2{ps2.x + ps2.y, pq2.x + pq2.y};
    __syncthreads();  // sync1
    float sm = 0.f, sq = 0.f;
#pragma unroll
    for (int w = 0; w < 8; ++w) {
      f32x2 v = *(const f32x2*)(lnred + (w * 64 + lane) * 2);
      sm += v.x; sq += v.y;
    }
    float mu = sm * (1.f / 64.f);
    float var = sq * (1.f / 64.f) - mu * mu;
    float rstd = rsqrtf(var + 1e-5f);
#pragma unroll
    for (int j = 0; j < 8; ++j) {
      int s = wv * 8 + j;  // pixel index owned by this wave
      float hvj = (j & 1) ? hv2[j >> 1].y : hv2[j >> 1].x;
      float nv = (hvj - mu) * rstd * lnw[e * 64 + s] + lnb[e * 64 + s];
      hbf[s * 72 + lane] = f2bf(nv);  // h[px][c] bf16, stride 72
    }
    __syncthreads();  // sync2: h ready

    // ---- pw_in (64->128) MFMA; wave owns A-rows [16wi,+16), G-rows +64,
    //      px-tiles {2jh, 2jh+1}
    const unsigned short* wInE = wInBf + (size_t)e * 8192;
    short8 aA[2], aG[2];
#pragma unroll
    for (int kf = 0; kf < 2; ++kf) {
      aA[kf] = *(const short8*)(wInE + (16 * wi + r15) * 64 + kf * 32 + r4 * 8);
      aG[kf] = *(const short8*)(wInE + (64 + 16 * wi + r15) * 64 + kf * 32 + r4 * 8);
    }
    f32x4 accA[2], accG[2];
#pragma unroll
    for (int ntl = 0; ntl < 2; ++ntl)
#pragma unroll
      for (int v = 0; v < 4; ++v) {
        accA[ntl][v] = pwin_b[e * 128 + 16 * wi + r4 * 4 + v];
        accG[ntl][v] = pwin_b[e * 128 + 64 + 16 * wi + r4 * 4 + v];
      }
#pragma unroll
    for (int ntl = 0; ntl < 2; ++ntl) {
      const int nt = 2 * jh + ntl;
#pragma unroll
      for (int kf = 0; kf < 2; ++kf) {
        short8 bfr = *(const short8*)(hbf + (16 * nt + r15) * 72 + kf * 32 + r4 * 8);
        accA[ntl] = __builtin_amdgcn_mfma_f32_16x16x32_bf16(aA[kf], bfr, accA[ntl], 0, 0, 0);
        accG[ntl] = __builtin_amdgcn_mfma_f32_16x16x32_bf16(aG[kf], bfr, accG[ntl], 0, 0, 0);
      }
    }
    // silu(a)*g -> h3 (separate buffer, packed uint2 = 4 bf16 channels)
#pragma unroll
    for (int ntl = 0; ntl < 2; ++ntl) {
      const int nt = 2 * jh + ntl;
      float hval[4];
#pragma unroll
      for (int v = 0; v < 4; ++v) {
        float a = accA[ntl][v];
        float g = accG[ntl][v];
        hval[v] = __fdividef(a, 1.f + __expf(-a)) * g;
      }
      uint2 w2;
      w2.x = (unsigned)f2bf(hval[0]) | ((unsigned)f2bf(hval[1]) << 16);
      w2.y = (unsigned)f2bf(hval[2]) | ((unsigned)f2bf(hval[3]) << 16);
      *(uint2*)(h3bf + (16 * nt + r15) * 72 + 16 * wi + 4 * r4) = w2;
    }
    __syncthreads();  // sync3: h3 ready

    // ---- pw_out (64->64) MFMA; wave owns rows [16wi,+16), px-tiles {2jh,+1}
    const unsigned short* wOutE = wOutBf + (size_t)e * 4096;
    short8 aO[2];
#pragma unroll
    for (int kf = 0; kf < 2; ++kf)
      aO[kf] = *(const short8*)(wOutE + (16 * wi + r15) * 64 + kf * 32 + r4 * 8);
    f32x4 accO[2];
#pragma unroll
    for (int ntl = 0; ntl < 2; ++ntl)
#pragma unroll
      for (int v = 0; v < 4; ++v) accO[ntl][v] = 0.f;
#pragma unroll
    for (int ntl = 0; ntl < 2; ++ntl) {
      const int nt = 2 * jh + ntl;
#pragma unroll
      for (int kf = 0; kf < 2; ++kf) {
        short8 bfr = *(const short8*)(h3bf + (16 * nt + r15) * 72 + kf * 32 + r4 * 8);
        accO[ntl] = __builtin_amdgcn_mfma_f32_16x16x32_bf16(aO[kf], bfr, accO[ntl], 0, 0, 0);
      }
    }
    float bO[4];
#pragma unroll
    for (int v = 0; v < 4; ++v) bO[v] = pwout_b[e * 64 + 16 * wi + r4 * 4 + v];
#pragma unroll
    for (int ntl = 0; ntl < 2; ++ntl)
#pragma unroll
      for (int v = 0; v < 4; ++v) oacc[ntl * 4 + v] += we * (accO[ntl][v] + bO[v]);
  }

  // ---- epilogue: eb aliases wsdw+hbf[0:3072); wsdw last read before sync1,
  //      hbf last read before sync3 -> safe to write now; h3bf (pw_out reads,
  //      possibly still in flight on other waves) is NOT aliased.
#pragma unroll
  for (int ntl = 0; ntl < 2; ++ntl)
#pragma unroll
    for (int v = 0; v < 4; ++v)
      eb[(16 * wi + 4 * r4 + v) * 68 + 16 * (2 * jh + ntl) + r15] = oacc[ntl * 4 + v];
  __syncthreads();
#pragma unroll
  for (int it = 0; it < 2; ++it) {
    int g = it * 512 + t;
    int c = g >> 4, q = g & 15;
    float4 dv = *(const float4*)(eb + c * 68 + q * 4);
    int rs = (q >> 1) ^ ((c >> 3) & 7);
    float4 xv = *(const float4*)(xs + c * 68 + rs * 8 + (q & 1) * 4);
    float4 o4 = {xv.x + dv.x, xv.y + dv.y, xv.z + dv.z, xv.w + dv.w};
    *(float4*)(out + obase + (size_t)c * 131072 + (q >> 1) * 128 + (q & 1) * 4) = o4;
  }
}

extern "C" void kernel_launch(void* const* d_in, const int* in_sizes, int n_in,
                              void* d_out, int out_size, void* d_ws, size_t ws_size,
                              hipStream_t stream) {
  const float* x       = (const float*)d_in[0];
  const float* rw      = (const float*)d_in[1];
  const float* rb      = (const float*)d_in[2];
  const float* dww     = (const float*)d_in[3];
  const float* dwb     = (const float*)d_in[4];
  const float* lnw     = (const float*)d_in[5];
  const float* lnb     = (const float*)d_in[6];
  const float* pwin_w  = (const float*)d_in[7];
  const float* pwin_b  = (const float*)d_in[8];
  const float* pwout_w = (const float*)d_in[9];
  const float* pwout_b = (const float*)d_in[10];
  float* out = (float*)d_out;

  char* ws = (char*)d_ws;
  float*          partial_l = (float*)ws;
  float*          dwT       = (float*)(ws + 1048576);
  int*            sel_i     = (int*)(ws + 1163264);
  float*          sel_w     = (float*)(ws + 1167360);
  unsigned short* wInBf     = (unsigned short*)(ws + 1171456);
  unsigned short* wOutBf    = (unsigned short*)(ws + 1302528);
  float*          xr        = (float*)(ws + 1368064);

  const bool repack = ws_size >= REPACK_NEED;

  hipLaunchKernelGGL(k_pre, dim3(496), dim3(256), 0, stream,
                     dww, pwin_w, pwout_w, dwT, wInBf, wOutBf);
  if (repack)
    hipLaunchKernelGGL(k_repack, dim3(2048), dim3(256), 0, stream, x, xr, partial_l);
  else
    hipLaunchKernelGGL(k_sum, dim3(512), dim3(256), 0, stream, x, partial_l);
  hipLaunchKernelGGL(k_router, dim3(512), dim3(64), 0, stream,
                     partial_l, rw, rb, sel_i, sel_w);
  if (repack)
    hipLaunchKernelGGL((k_main<true>), dim3(4096), dim3(512), 0, stream,
                       x, xr, dwT, dwb, lnw, lnb, pwin_b, pwout_b,
                       wInBf, wOutBf, sel_i, sel_w, out);
  else
    hipLaunchKernelGGL((k_main<false>), dim3(4096), dim3(512), 0, stream,
                       x, xr, dwT, dwb, lnw, lnb, pwin_b, pwout_b,
                       wInBf, wOutBf, sel_i, sel_w, out);
}

// Round 11
// 159.264 us; speedup vs baseline: 1.0326x; 1.0326x over previous
//
#include <hip/hip_runtime.h>
#include <hip/hip_bf16.h>
#include <cstddef>
#include <cstdint>

// SpatialPatchMoE on MI355X (gfx950).
// x[2,64,8,128,128] f32 -> 512 patches x 8 l-slices; router top-2/8;
// per expert: dwconv(1,7,7) -> LN(8,8) -> pw 64->128 -> silu*gate -> pw 64->64;
// out = x + sum_k w_k * expert_k.  Pointwise matmuls = bf16 MFMA 16x16x32.
//
// k_main: 512 threads = 8 waves; wave wv owns conv row wv and MFMA row-tile
// (wv>>1) x px-half (wv&1).  NO __launch_bounds__ min-waves (rounds 4-6: any
// min-waves cap makes the allocator spill 300-500 MB of scratch).
// Round 11 = round-8 base (weights [tap][c] stride-64 ds_read_b32, zero
// conflicts; round-10's [c][7][8] layout was a 16-way conflict, 25.5M cyc)
// + P/S pair conv scheme (24 pk_fma + 5 S-pair builds per row)
// + __fdividef silu + f32x2-packed lnred.
//
// ws layout (bytes):
//   partial_l : f32 [n][l][c]      @ 0         (1048576)
//   dwT       : f32 [e][tap][c]    @ 1048576   (100352)
//   sel_i     : int[2*512]         @ 1148928   (4096)
//   sel_w     : f32[2*512]         @ 1153024   (4096)
//   wInBf     : bf16 [e][128][64]  @ 1157120   (131072)
//   wOutBf    : bf16 [e][64][64]   @ 1288192   (65536)
//   xr        : f32 [n*8+l][c][px] @ 1353728   (67108864)   (repack path)

typedef __attribute__((ext_vector_type(8))) short short8;
typedef __attribute__((ext_vector_type(4))) float f32x4;
typedef __attribute__((ext_vector_type(2))) float f32x2;

#define REPACK_NEED 68462592ull

__device__ __forceinline__ unsigned short f2bf(float f) {
  return __builtin_bit_cast(unsigned short, __float2bfloat16(f));
}

__device__ __forceinline__ float wave_sum64(float v) {
#pragma unroll
  for (int m = 32; m > 0; m >>= 1) v += __shfl_xor(v, m, 64);
  return v;
}

// ---------------- preprocess: dw transpose + pw weights -> bf16
__global__ void k_pre(const float* __restrict__ dw,
                      const float* __restrict__ pwin,
                      const float* __restrict__ pwout,
                      float* __restrict__ dwT,
                      unsigned short* __restrict__ wIn,
                      unsigned short* __restrict__ wOut) {
  int idx = blockIdx.x * 256 + threadIdx.x;
  if (idx < 25088) {
    int e = idx / 3136;
    int r = idx - e * 3136;
    int c = r / 49;
    int tap = r - c * 49;
    dwT[(e * 49 + tap) * 64 + c] = dw[idx];
  } else if (idx < 25088 + 65536) {
    int i = idx - 25088;
    wIn[i] = f2bf(pwin[i]);
  } else if (idx < 25088 + 65536 + 32768) {
    int i = idx - 90624;
    wOut[i] = f2bf(pwout[i]);
  }
}

// ---------------- fallback patch sums (only when ws too small for repack)
__global__ __launch_bounds__(256) void k_sum(const float* __restrict__ x,
                                             float* __restrict__ partial_l) {
  __shared__ float red[256 * 17];
  int t = threadIdx.x, bid = blockIdx.x;
  int b = bid >> 8, c = (bid >> 2) & 63, lp = bid & 3;
  const float4* x4 = (const float4*)x + ((size_t)((b * 64 + c) * 8) + lp * 2) * 4096;
#pragma unroll 1
  for (int l2 = 0; l2 < 2; ++l2) {
    float acc[16];
#pragma unroll
    for (int k = 0; k < 16; ++k) acc[k] = 0.f;
#pragma unroll
    for (int k = 0; k < 16; ++k) {
      float4 v = x4[l2 * 4096 + k * 256 + t];
      acc[k] += v.x + v.y + v.z + v.w;
    }
    int pcol = (t & 31) >> 1;
    int slot = ((t & 1) << 3) | (t >> 5);
    __syncthreads();
#pragma unroll
    for (int k = 0; k < 16; ++k) red[(k * 16 + pcol) * 17 + slot] = acc[k];
    __syncthreads();
    float s = 0.f;
#pragma unroll
    for (int j = 0; j < 16; ++j) s += red[t * 17 + j];
    partial_l[((size_t)(b * 256 + t)) * 512 + (lp * 2 + l2) * 64 + c] = s;
  }
}

// ---------------- repack x -> patch-major xr[(n*8+l)][c][px], fused patch sums
__global__ __launch_bounds__(256) void k_repack(const float* __restrict__ x,
                                                float* __restrict__ xr,
                                                float* __restrict__ partial_l) {
  __shared__ __align__(16) float lt[8 * 1060];
  int t = threadIdx.x, bid = blockIdx.x;
  int ct = bid & 7, hh = (bid >> 3) & 15, l = (bid >> 7) & 7, b = bid >> 10;
  int c0 = ct * 8;
  const float4* x4 = (const float4*)x;
  float4* xr4 = (float4*)xr;
  int y = t >> 5, xq = t & 31;
#pragma unroll
  for (int i = 0; i < 8; ++i) {
    size_t src = ((size_t)((b * 64 + c0 + i) * 8 + l) << 12) +
                 (size_t)(hh * 8 + y) * 32 + xq;
    float4 v = x4[src];
    *(float4*)(lt + i * 1060 + y * 132 + xq * 4) = v;
  }
  __syncthreads();
  int cc = (t >> 4) & 7, ihalf = t >> 7, pxq = t & 15;
  int py = pxq >> 1, xcol = pxq & 1;
#pragma unroll
  for (int iw = 0; iw < 8; ++iw) {
    int ww = ihalf * 8 + iw;
    float4 v = *(const float4*)(lt + cc * 1060 + py * 132 + ww * 8 + xcol * 4);
    int n = b * 256 + hh * 16 + ww;
    xr4[((size_t)(n * 8 + l) << 10) + (c0 + cc) * 16 + pxq] = v;
    float s = v.x + v.y + v.z + v.w;
#pragma unroll
    for (int m = 1; m < 16; m <<= 1) s += __shfl_xor(s, m, 64);
    if (pxq == 0) partial_l[(size_t)(n * 8 + l) * 64 + c0 + cc] = s;
  }
}

// ---------------- router
__global__ void k_router(const float* __restrict__ partial_l,
                         const float* __restrict__ rw, const float* __restrict__ rb,
                         int* __restrict__ sel_i, float* __restrict__ sel_w) {
  int n = blockIdx.x;
  int lane = threadIdx.x;
  float s = 0.f;
#pragma unroll
  for (int l = 0; l < 8; ++l)
    s += partial_l[(size_t)n * 512 + l * 64 + lane];
  float rin = s * (1.f / 512.f);
  float lg[8];
#pragma unroll
  for (int e = 0; e < 8; ++e) {
    float v = rin * rw[e * 64 + lane];
    lg[e] = wave_sum64(v) + rb[e];
  }
  int e0 = 0; float v0 = lg[0];
#pragma unroll
  for (int e = 1; e < 8; ++e) if (lg[e] > v0) { v0 = lg[e]; e0 = e; }
  int e1 = -1; float v1 = -1e30f;
#pragma unroll
  for (int e = 0; e < 8; ++e) if (e != e0 && lg[e] > v1) { v1 = lg[e]; e1 = e; }
  if (lane == 0) {
    float w1 = __expf(v1 - v0);
    float z = 1.f + w1;
    sel_i[2 * n] = e0; sel_i[2 * n + 1] = e1;
    sel_w[2 * n] = 1.f / z; sel_w[2 * n + 1] = w1 / z;
  }
}

// ---------------- main: one block per (patch n, depth l); 8 waves of 64
template <bool REPACK>
__global__ __launch_bounds__(512) void k_main(
    const float* __restrict__ x, const float* __restrict__ xr,
    const float* __restrict__ dwT, const float* __restrict__ dwb,
    const float* __restrict__ lnw, const float* __restrict__ lnb,
    const float* __restrict__ pwin_b, const float* __restrict__ pwout_b,
    const unsigned short* __restrict__ wInBf,
    const unsigned short* __restrict__ wOutBf,
    const int* __restrict__ sel_i, const float* __restrict__ sel_w,
    float* __restrict__ out) {
  // carve: wsdw f32[49*64] @0 (12544) | hbf u16[64*72] @12544 (9216)
  //        | h3bf u16[64*72] @21760 (9216) | lnred f32x2[8*64] @30976 (4096)
  //        | xs f32[64*68] @35072 (17408)  => 52480 B (3 blocks/CU)
  __shared__ __align__(16) char smem[52480];
  float* wsdw          = (float*)smem;
  unsigned short* hbf  = (unsigned short*)(smem + 12544);
  unsigned short* h3bf = (unsigned short*)(smem + 21760);
  float* lnred         = (float*)(smem + 30976);
  float* xs            = (float*)(smem + 35072);
  float* eb            = (float*)smem;  // epilogue alias over wsdw+hbf[0:4864)

  const int t = threadIdx.x;
  const int lane = t & 63;
  const int wv = __builtin_amdgcn_readfirstlane(t >> 6);  // 0..7
  const int wi = wv >> 1;      // MFMA row-tile index 0..3
  const int jh = wv & 1;       // px-half 0..1
  const int r15 = lane & 15, r4 = lane >> 4;
  const int bidx = blockIdx.x;
  const int n = bidx >> 3, l = bidx & 7;
  const int b = n >> 8, p = n & 255;
  const int hh = p >> 4, ww = p & 15;
  const size_t obase = (size_t)b * 8388608 + (size_t)l * 16384 +
                       (size_t)hh * 1024 + (size_t)ww * 8;

  // ---- stage x slice -> xs [c][px], stride 68, XOR row swizzle r^((c>>3)&7)
#pragma unroll
  for (int it = 0; it < 2; ++it) {
    int g = it * 512 + t;
    int c = g >> 4, q = g & 15;
    float4 v;
    if constexpr (REPACK)
      v = ((const float4*)xr)[(size_t)bidx * 1024 + g];
    else
      v = *(const float4*)(x + obase + (size_t)c * 131072 + (q >> 1) * 128 + (q & 1) * 4);
    int rs = (q >> 1) ^ ((c >> 3) & 7);
    *(float4*)(xs + c * 68 + rs * 8 + (q & 1) * 4) = v;
  }
  // no barrier: syncW below covers xs too

  float oacc[8];
#pragma unroll
  for (int i = 0; i < 8; ++i) oacc[i] = 0.f;

#pragma unroll 1
  for (int k = 0; k < 2; ++k) {
    const int e = __builtin_amdgcn_readfirstlane(sel_i[2 * n + k]);
    const float we = sel_w[2 * n + k];

    // ---- stage expert dw weights into LDS: [tap][c] = 784 float4
    {
      const float4* src = (const float4*)(dwT + e * 3136);
      float4* dst = (float4*)wsdw;
      dst[t] = src[t];
      if (t < 272) dst[512 + t] = src[512 + t];
    }
    __syncthreads();  // syncW: wsdw + xs ready (k=0); guards hbf/h3bf reuse (k=1)

    // ---- depthwise conv: lane = channel; wave wv owns output row wv (8 px)
    //      P/S pair scheme: even pairs free from b128 halves, 5 shifted pairs
    //      built once per row; zero-operand FMAs elided; 24 pk_fma / row.
    f32x2 hv2[4];
    {
      const float bias = dwb[e * 64 + lane];
#pragma unroll
      for (int j = 0; j < 4; ++j) hv2[j] = f32x2{bias, bias};
    }
    {
      const float* rowbase = xs + lane * 68;
      const int rc = (lane >> 3) & 7;
      const float* wl = wsdw + lane;
      const int y0 = wv;
      const int rlo = (y0 - 3 < 0) ? 0 : y0 - 3;
      const int rhi = (y0 + 3 > 7) ? 7 : y0 + 3;
      for (int r = rlo; r <= rhi; ++r) {
        const float* xrow = rowbase + 8 * (r ^ rc);
        float4 a0 = *(const float4*)xrow;
        float4 a1 = *(const float4*)(xrow + 4);
        const float* wrow = wl + (r - y0 + 3) * 448;   // 7 taps * 64
        float w0 = wrow[0];
        float w1 = wrow[64];
        float w2 = wrow[128];
        float w3 = wrow[192];
        float w4 = wrow[256];
        float w5 = wrow[320];
        float w6 = wrow[384];
        f32x2 P2 = {a0.x, a0.y}, P3 = {a0.z, a0.w};
        f32x2 P4 = {a1.x, a1.y}, P5 = {a1.z, a1.w};
        f32x2 S1 = {0.f, a0.x}, S2 = {a0.y, a0.z}, S3 = {a0.w, a1.x};
        f32x2 S4 = {a1.y, a1.z}, S5 = {a1.w, 0.f};
#define FMA2(J, PAIR, W) hv2[J] = __builtin_elementwise_fma(PAIR, f32x2{W, W}, hv2[J])
        // dx=0 (S_J):     J=0 all-zero pair -> elided
        FMA2(1, S1, w0); FMA2(2, S2, w0); FMA2(3, S3, w0);
        // dx=1 (P_{J+1}): J=0 all-zero pair -> elided
        FMA2(1, P2, w1); FMA2(2, P3, w1); FMA2(3, P4, w1);
        // dx=2 (S_{J+1}):
        FMA2(0, S1, w2); FMA2(1, S2, w2); FMA2(2, S3, w2); FMA2(3, S4, w2);
        // dx=3 (P_{J+2}):
        FMA2(0, P2, w3); FMA2(1, P3, w3); FMA2(2, P4, w3); FMA2(3, P5, w3);
        // dx=4 (S_{J+2}):
        FMA2(0, S2, w4); FMA2(1, S3, w4); FMA2(2, S4, w4); FMA2(3, S5, w4);
        // dx=5 (P_{J+3}): J=3 out of range -> elided
        FMA2(0, P3, w5); FMA2(1, P4, w5); FMA2(2, P5, w5);
        // dx=6 (S_{J+3}): J=3 out of range -> elided
        FMA2(0, S3, w6); FMA2(1, S4, w6); FMA2(2, S5, w6);
#undef FMA2
      }
    }

    // ---- LayerNorm over 64 pixels per channel (8 wave-partials, f32x2)
    f32x2 ps2 = f32x2{0.f, 0.f}, pq2 = f32x2{0.f, 0.f};
#pragma unroll
    for (int j = 0; j < 4; ++j) {
      ps2 += hv2[j];
      pq2 = __builtin_elementwise_fma(hv2[j], hv2[j], pq2);
    }
    *(f32x2*)(lnred + (wv * 64 + lane) * 2) = f32x2{ps2.x + ps2.y, pq2.x + pq2.y};
    __syncthreads();  // sync1
    float sm = 0.f, sq = 0.f;
#pragma unroll
    for (int w = 0; w < 8; ++w) {
      f32x2 v = *(const f32x2*)(lnred + (w * 64 + lane) * 2);
      sm += v.x; sq += v.y;
    }
    float mu = sm * (1.f / 64.f);
    float var = sq * (1.f / 64.f) - mu * mu;
    float rstd = rsqrtf(var + 1e-5f);
#pragma unroll
    for (int j = 0; j < 8; ++j) {
      int s = wv * 8 + j;  // pixel index owned by this wave
      float hvj = (j & 1) ? hv2[j >> 1].y : hv2[j >> 1].x;
      float nv = (hvj - mu) * rstd * lnw[e * 64 + s] + lnb[e * 64 + s];
      hbf[s * 72 + lane] = f2bf(nv);  // h[px][c] bf16, stride 72
    }
    __syncthreads();  // sync2: h ready

    // ---- pw_in (64->128) MFMA; wave owns A-rows [16wi,+16), G-rows +64,
    //      px-tiles {2jh, 2jh+1}
    const unsigned short* wInE = wInBf + (size_t)e * 8192;
    short8 aA[2], aG[2];
#pragma unroll
    for (int kf = 0; kf < 2; ++kf) {
      aA[kf] = *(const short8*)(wInE + (16 * wi + r15) * 64 + kf * 32 + r4 * 8);
      aG[kf] = *(const short8*)(wInE + (64 + 16 * wi + r15) * 64 + kf * 32 + r4 * 8);
    }
    f32x4 accA[2], accG[2];
#pragma unroll
    for (int ntl = 0; ntl < 2; ++ntl)
#pragma unroll
      for (int v = 0; v < 4; ++v) {
        accA[ntl][v] = pwin_b[e * 128 + 16 * wi + r4 * 4 + v];
        accG[ntl][v] = pwin_b[e * 128 + 64 + 16 * wi + r4 * 4 + v];
      }
#pragma unroll
    for (int ntl = 0; ntl < 2; ++ntl) {
      const int nt = 2 * jh + ntl;
#pragma unroll
      for (int kf = 0; kf < 2; ++kf) {
        short8 bfr = *(const short8*)(hbf + (16 * nt + r15) * 72 + kf * 32 + r4 * 8);
        accA[ntl] = __builtin_amdgcn_mfma_f32_16x16x32_bf16(aA[kf], bfr, accA[ntl], 0, 0, 0);
        accG[ntl] = __builtin_amdgcn_mfma_f32_16x16x32_bf16(aG[kf], bfr, accG[ntl], 0, 0, 0);
      }
    }
    // silu(a)*g -> h3 (separate buffer, packed uint2 = 4 bf16 channels)
#pragma unroll
    for (int ntl = 0; ntl < 2; ++ntl) {
      const int nt = 2 * jh + ntl;
      float hval[4];
#pragma unroll
      for (int v = 0; v < 4; ++v) {
        float a = accA[ntl][v];
        float g = accG[ntl][v];
        hval[v] = __fdividef(a, 1.f + __expf(-a)) * g;
      }
      uint2 w2;
      w2.x = (unsigned)f2bf(hval[0]) | ((unsigned)f2bf(hval[1]) << 16);
      w2.y = (unsigned)f2bf(hval[2]) | ((unsigned)f2bf(hval[3]) << 16);
      *(uint2*)(h3bf + (16 * nt + r15) * 72 + 16 * wi + 4 * r4) = w2;
    }
    __syncthreads();  // sync3: h3 ready

    // ---- pw_out (64->64) MFMA; wave owns rows [16wi,+16), px-tiles {2jh,+1}
    const unsigned short* wOutE = wOutBf + (size_t)e * 4096;
    short8 aO[2];
#pragma unroll
    for (int kf = 0; kf < 2; ++kf)
      aO[kf] = *(const short8*)(wOutE + (16 * wi + r15) * 64 + kf * 32 + r4 * 8);
    f32x4 accO[2];
#pragma unroll
    for (int ntl = 0; ntl < 2; ++ntl)
#pragma unroll
      for (int v = 0; v < 4; ++v) accO[ntl][v] = 0.f;
#pragma unroll
    for (int ntl = 0; ntl < 2; ++ntl) {
      const int nt = 2 * jh + ntl;
#pragma unroll
      for (int kf = 0; kf < 2; ++kf) {
        short8 bfr = *(const short8*)(h3bf + (16 * nt + r15) * 72 + kf * 32 + r4 * 8);
        accO[ntl] = __builtin_amdgcn_mfma_f32_16x16x32_bf16(aO[kf], bfr, accO[ntl], 0, 0, 0);
      }
    }
    float bO[4];
#pragma unroll
    for (int v = 0; v < 4; ++v) bO[v] = pwout_b[e * 64 + 16 * wi + r4 * 4 + v];
#pragma unroll
    for (int ntl = 0; ntl < 2; ++ntl)
#pragma unroll
      for (int v = 0; v < 4; ++v) oacc[ntl * 4 + v] += we * (accO[ntl][v] + bO[v]);
  }

  // ---- epilogue: eb aliases wsdw+hbf[0:4864); wsdw last read before sync1,
  //      hbf last read before sync3 -> safe to write now; h3bf (read by
  //      pw_out, possibly in flight on other waves) is NOT aliased.
#pragma unroll
  for (int ntl = 0; ntl < 2; ++ntl)
#pragma unroll
    for (int v = 0; v < 4; ++v)
      eb[(16 * wi + 4 * r4 + v) * 68 + 16 * (2 * jh + ntl) + r15] = oacc[ntl * 4 + v];
  __syncthreads();
#pragma unroll
  for (int it = 0; it < 2; ++it) {
    int g = it * 512 + t;
    int c = g >> 4, q = g & 15;
    float4 dv = *(const float4*)(eb + c * 68 + q * 4);
    int rs = (q >> 1) ^ ((c >> 3) & 7);
    float4 xv = *(const float4*)(xs + c * 68 + rs * 8 + (q & 1) * 4);
    float4 o4 = {xv.x + dv.x, xv.y + dv.y, xv.z + dv.z, xv.w + dv.w};
    *(float4*)(out + obase + (size_t)c * 131072 + (q >> 1) * 128 + (q & 1) * 4) = o4;
  }
}

extern "C" void kernel_launch(void* const* d_in, const int* in_sizes, int n_in,
                              void* d_out, int out_size, void* d_ws, size_t ws_size,
                              hipStream_t stream) {
  const float* x       = (const float*)d_in[0];
  const float* rw      = (const float*)d_in[1];
  const float* rb      = (const float*)d_in[2];
  const float* dww     = (const float*)d_in[3];
  const float* dwb     = (const float*)d_in[4];
  const float* lnw     = (const float*)d_in[5];
  const float* lnb     = (const float*)d_in[6];
  const float* pwin_w  = (const float*)d_in[7];
  const float* pwin_b  = (const float*)d_in[8];
  const float* pwout_w = (const float*)d_in[9];
  const float* pwout_b = (const float*)d_in[10];
  float* out = (float*)d_out;

  char* ws = (char*)d_ws;
  float*          partial_l = (float*)ws;
  float*          dwT       = (float*)(ws + 1048576);
  int*            sel_i     = (int*)(ws + 1148928);
  float*          sel_w     = (float*)(ws + 1153024);
  unsigned short* wInBf     = (unsigned short*)(ws + 1157120);
  unsigned short* wOutBf    = (unsigned short*)(ws + 1288192);
  float*          xr        = (float*)(ws + 1353728);

  const bool repack = ws_size >= REPACK_NEED;

  hipLaunchKernelGGL(k_pre, dim3(482), dim3(256), 0, stream,
                     dww, pwin_w, pwout_w, dwT, wInBf, wOutBf);
  if (repack)
    hipLaunchKernelGGL(k_repack, dim3(2048), dim3(256), 0, stream, x, xr, partial_l);
  else
    hipLaunchKernelGGL(k_sum, dim3(512), dim3(256), 0, stream, x, partial_l);
  hipLaunchKernelGGL(k_router, dim3(512), dim3(64), 0, stream,
                     partial_l, rw, rb, sel_i, sel_w);
  if (repack)
    hipLaunchKernelGGL((k_main<true>), dim3(4096), dim3(512), 0, stream,
                       x, xr, dwT, dwb, lnw, lnb, pwin_b, pwout_b,
                       wInBf, wOutBf, sel_i, sel_w, out);
  else
    hipLaunchKernelGGL((k_main<false>), dim3(4096), dim3(512), 0, stream,
                       x, xr, dwT, dwb, lnw, lnb, pwin_b, pwout_b,
                       wInBf, wOutBf, sel_i, sel_w, out);
}

// Round 12
// 146.228 us; speedup vs baseline: 1.1247x; 1.0891x over previous
//
#include <hip/hip_runtime.h>
#include <hip/hip_bf16.h>
#include <cstddef>
#include <cstdint>

// SpatialPatchMoE on MI355X (gfx950).
// x[2,64,8,128,128] f32 -> 512 patches x 8 l-slices; router top-2/8;
// per expert: dwconv(1,7,7) -> LN(8,8) -> pw 64->128 -> silu*gate -> pw 64->64;
// out = x + sum_k w_k * expert_k.  Pointwise matmuls = bf16 MFMA 16x16x32.
//
// k_main: 512 threads = 8 waves; wave wv owns conv row wv and MFMA row-tile
// (wv>>1) x px-half (wv&1).  NO __launch_bounds__ min-waves (rounds 4-6: any
// min-waves cap makes the allocator spill 300-500 MB of scratch).
// Round 12 = round-8 inner code exactly (best measured, 125 us k_main), with
// an LDS diet for 4 blocks/CU: bf16 conv weights (6.3KB), bf16 xs (9.2KB),
// residual re-read from global xr in the epilogue.  LDS 52.5 -> 38.0 KB.
//
// ws layout (bytes):
//   partial_l : f32 [n][l][c]       @ 0         (1048576)
//   dwTbf     : bf16 [e][tap][c]    @ 1048576   (50176)
//   sel_i     : int[2*512]          @ 1098752   (4096)
//   sel_w     : f32[2*512]          @ 1102848   (4096)
//   wInBf     : bf16 [e][128][64]   @ 1106944   (131072)
//   wOutBf    : bf16 [e][64][64]    @ 1238016   (65536)
//   xr        : f32 [n*8+l][c][px]  @ 1303552   (67108864)   (repack path)

typedef __attribute__((ext_vector_type(8))) short short8;
typedef __attribute__((ext_vector_type(4))) float f32x4;
typedef __attribute__((ext_vector_type(2))) float f32x2;

#define REPACK_NEED 68412416ull

__device__ __forceinline__ unsigned short f2bf(float f) {
  return __builtin_bit_cast(unsigned short, __float2bfloat16(f));
}
__device__ __forceinline__ float bflo(unsigned u) {
  return __builtin_bit_cast(float, u << 16);
}
__device__ __forceinline__ float bfhi(unsigned u) {
  return __builtin_bit_cast(float, u & 0xFFFF0000u);
}

__device__ __forceinline__ float wave_sum64(float v) {
#pragma unroll
  for (int m = 32; m > 0; m >>= 1) v += __shfl_xor(v, m, 64);
  return v;
}

// ---------------- preprocess: dw transpose->bf16 + pw weights -> bf16
__global__ void k_pre(const float* __restrict__ dw,
                      const float* __restrict__ pwin,
                      const float* __restrict__ pwout,
                      unsigned short* __restrict__ dwTbf,
                      unsigned short* __restrict__ wIn,
                      unsigned short* __restrict__ wOut) {
  int idx = blockIdx.x * 256 + threadIdx.x;
  if (idx < 25088) {
    int e = idx / 3136;
    int r = idx - e * 3136;
    int c = r / 49;
    int tap = r - c * 49;
    dwTbf[(e * 49 + tap) * 64 + c] = f2bf(dw[idx]);
  } else if (idx < 25088 + 65536) {
    int i = idx - 25088;
    wIn[i] = f2bf(pwin[i]);
  } else if (idx < 25088 + 65536 + 32768) {
    int i = idx - 90624;
    wOut[i] = f2bf(pwout[i]);
  }
}

// ---------------- fallback patch sums (only when ws too small for repack)
__global__ __launch_bounds__(256) void k_sum(const float* __restrict__ x,
                                             float* __restrict__ partial_l) {
  __shared__ float red[256 * 17];
  int t = threadIdx.x, bid = blockIdx.x;
  int b = bid >> 8, c = (bid >> 2) & 63, lp = bid & 3;
  const float4* x4 = (const float4*)x + ((size_t)((b * 64 + c) * 8) + lp * 2) * 4096;
#pragma unroll 1
  for (int l2 = 0; l2 < 2; ++l2) {
    float acc[16];
#pragma unroll
    for (int k = 0; k < 16; ++k) acc[k] = 0.f;
#pragma unroll
    for (int k = 0; k < 16; ++k) {
      float4 v = x4[l2 * 4096 + k * 256 + t];
      acc[k] += v.x + v.y + v.z + v.w;
    }
    int pcol = (t & 31) >> 1;
    int slot = ((t & 1) << 3) | (t >> 5);
    __syncthreads();
#pragma unroll
    for (int k = 0; k < 16; ++k) red[(k * 16 + pcol) * 17 + slot] = acc[k];
    __syncthreads();
    float s = 0.f;
#pragma unroll
    for (int j = 0; j < 16; ++j) s += red[t * 17 + j];
    partial_l[((size_t)(b * 256 + t)) * 512 + (lp * 2 + l2) * 64 + c] = s;
  }
}

// ---------------- repack x -> patch-major xr[(n*8+l)][c][px], fused patch sums
__global__ __launch_bounds__(256) void k_repack(const float* __restrict__ x,
                                                float* __restrict__ xr,
                                                float* __restrict__ partial_l) {
  __shared__ __align__(16) float lt[8 * 1060];
  int t = threadIdx.x, bid = blockIdx.x;
  int ct = bid & 7, hh = (bid >> 3) & 15, l = (bid >> 7) & 7, b = bid >> 10;
  int c0 = ct * 8;
  const float4* x4 = (const float4*)x;
  float4* xr4 = (float4*)xr;
  int y = t >> 5, xq = t & 31;
#pragma unroll
  for (int i = 0; i < 8; ++i) {
    size_t src = ((size_t)((b * 64 + c0 + i) * 8 + l) << 12) +
                 (size_t)(hh * 8 + y) * 32 + xq;
    float4 v = x4[src];
    *(float4*)(lt + i * 1060 + y * 132 + xq * 4) = v;
  }
  __syncthreads();
  int cc = (t >> 4) & 7, ihalf = t >> 7, pxq = t & 15;
  int py = pxq >> 1, xcol = pxq & 1;
#pragma unroll
  for (int iw = 0; iw < 8; ++iw) {
    int ww = ihalf * 8 + iw;
    float4 v = *(const float4*)(lt + cc * 1060 + py * 132 + ww * 8 + xcol * 4);
    int n = b * 256 + hh * 16 + ww;
    xr4[((size_t)(n * 8 + l) << 10) + (c0 + cc) * 16 + pxq] = v;
    float s = v.x + v.y + v.z + v.w;
#pragma unroll
    for (int m = 1; m < 16; m <<= 1) s += __shfl_xor(s, m, 64);
    if (pxq == 0) partial_l[(size_t)(n * 8 + l) * 64 + c0 + cc] = s;
  }
}

// ---------------- router
__global__ void k_router(const float* __restrict__ partial_l,
                         const float* __restrict__ rw, const float* __restrict__ rb,
                         int* __restrict__ sel_i, float* __restrict__ sel_w) {
  int n = blockIdx.x;
  int lane = threadIdx.x;
  float s = 0.f;
#pragma unroll
  for (int l = 0; l < 8; ++l)
    s += partial_l[(size_t)n * 512 + l * 64 + lane];
  float rin = s * (1.f / 512.f);
  float lg[8];
#pragma unroll
  for (int e = 0; e < 8; ++e) {
    float v = rin * rw[e * 64 + lane];
    lg[e] = wave_sum64(v) + rb[e];
  }
  int e0 = 0; float v0 = lg[0];
#pragma unroll
  for (int e = 1; e < 8; ++e) if (lg[e] > v0) { v0 = lg[e]; e0 = e; }
  int e1 = -1; float v1 = -1e30f;
#pragma unroll
  for (int e = 0; e < 8; ++e) if (e != e0 && lg[e] > v1) { v1 = lg[e]; e1 = e; }
  if (lane == 0) {
    float w1 = __expf(v1 - v0);
    float z = 1.f + w1;
    sel_i[2 * n] = e0; sel_i[2 * n + 1] = e1;
    sel_w[2 * n] = 1.f / z; sel_w[2 * n + 1] = w1 / z;
  }
}

// ---------------- main: one block per (patch n, depth l); 8 waves of 64
template <bool REPACK>
__global__ __launch_bounds__(512) void k_main(
    const float* __restrict__ x, const float* __restrict__ xr,
    const unsigned short* __restrict__ dwTbf, const float* __restrict__ dwb,
    const float* __restrict__ lnw, const float* __restrict__ lnb,
    const float* __restrict__ pwin_b, const float* __restrict__ pwout_b,
    const unsigned short* __restrict__ wInBf,
    const unsigned short* __restrict__ wOutBf,
    const int* __restrict__ sel_i, const float* __restrict__ sel_w,
    float* __restrict__ out) {
  // carve: wsdw u16[49*64] @0 (6272) | hbf u16[64*72] @6272 (9216)
  //        | h3bf u16[64*72] @15488 (9216) | lnred f32[16*64] @24704 (4096)
  //        | xsb u16[64*72] @28800 (9216)  => 38016 B -> 4 blocks/CU
  __shared__ __align__(16) char smem[38016];
  unsigned short* wsdw = (unsigned short*)smem;
  unsigned short* hbf  = (unsigned short*)(smem + 6272);
  unsigned short* h3bf = (unsigned short*)(smem + 15488);
  float* lnred         = (float*)(smem + 24704);
  unsigned short* xsb  = (unsigned short*)(smem + 28800);
  float* eb            = (float*)smem;  // epilogue alias [0,17408)

  const int t = threadIdx.x;
  const int lane = t & 63;
  const int wv = __builtin_amdgcn_readfirstlane(t >> 6);  // 0..7
  const int wi = wv >> 1;      // MFMA row-tile index 0..3
  const int jh = wv & 1;       // px-half 0..1
  const int r15 = lane & 15, r4 = lane >> 4;
  const int bidx = blockIdx.x;
  const int n = bidx >> 3, l = bidx & 7;
  const int b = n >> 8, p = n & 255;
  const int hh = p >> 4, ww = p & 15;
  const size_t obase = (size_t)b * 8388608 + (size_t)l * 16384 +
                       (size_t)hh * 1024 + (size_t)ww * 8;

  // ---- stage x slice -> xsb [c][px] bf16, stride 72, XOR row swizzle
#pragma unroll
  for (int it = 0; it < 2; ++it) {
    int g = it * 512 + t;
    int c = g >> 4, q = g & 15;
    float4 v;
    if constexpr (REPACK)
      v = ((const float4*)xr)[(size_t)bidx * 1024 + g];
    else
      v = *(const float4*)(x + obase + (size_t)c * 131072 + (q >> 1) * 128 + (q & 1) * 4);
    int rs = (q >> 1) ^ ((c >> 3) & 7);
    uint2 w2;
    w2.x = (unsigned)f2bf(v.x) | ((unsigned)f2bf(v.y) << 16);
    w2.y = (unsigned)f2bf(v.z) | ((unsigned)f2bf(v.w) << 16);
    *(uint2*)(xsb + c * 72 + rs * 8 + (q & 1) * 4) = w2;
  }
  // no barrier: syncW below covers xsb too

  float oacc[8];
#pragma unroll
  for (int i = 0; i < 8; ++i) oacc[i] = 0.f;

#pragma unroll 1
  for (int k = 0; k < 2; ++k) {
    const int e = __builtin_amdgcn_readfirstlane(sel_i[2 * n + k]);
    const float we = sel_w[2 * n + k];

    // ---- stage expert dw weights (bf16 [tap][c]) into LDS: 392 uint4
    {
      const uint4* src = (const uint4*)(dwTbf + e * 3136);
      uint4* dst = (uint4*)wsdw;
      if (t < 392) dst[t] = src[t];
    }
    __syncthreads();  // syncW: wsdw + xsb ready (k=0); guards hbf/h3bf reuse (k=1)

    // ---- depthwise conv: lane = channel; wave wv owns output row wv (8 px)
    //      r8's exact FMA structure; inputs/weights unpacked from bf16.
    f32x2 hv2[4];
    {
      const float bias = dwb[e * 64 + lane];
#pragma unroll
      for (int j = 0; j < 4; ++j) hv2[j] = f32x2{bias, bias};
    }
    {
      const unsigned short* rowbase = xsb + lane * 72;
      const int rc = (lane >> 3) & 7;
      const unsigned short* wl = wsdw + lane;
      const int y0 = wv;
      const int rlo = (y0 - 3 < 0) ? 0 : y0 - 3;
      const int rhi = (y0 + 3 > 7) ? 7 : y0 + 3;
      for (int r = rlo; r <= rhi; ++r) {   // runtime loop: small code, few regs
        uint4 xraw = *(const uint4*)(rowbase + (r ^ rc) * 8);
        float xp[14];
        xp[0] = 0.f; xp[1] = 0.f; xp[2] = 0.f;
        xp[3] = bflo(xraw.x); xp[4] = bfhi(xraw.x);
        xp[5] = bflo(xraw.y); xp[6] = bfhi(xraw.y);
        xp[7] = bflo(xraw.z); xp[8] = bfhi(xraw.z);
        xp[9] = bflo(xraw.w); xp[10] = bfhi(xraw.w);
        xp[11] = 0.f; xp[12] = 0.f; xp[13] = 0.f;
        f32x2 pr[13];
#pragma unroll
        for (int m = 0; m < 13; ++m) pr[m] = f32x2{xp[m], xp[m + 1]};
        const unsigned short* wrow = wl + (r - y0 + 3) * 448;   // 7 taps * 64
#pragma unroll
        for (int dx = 0; dx < 7; ++dx) {
          float wt = bflo((unsigned)wrow[dx * 64]);   // ds_read_u16 + lshl
          f32x2 w2 = f32x2{wt, wt};
          hv2[0] = __builtin_elementwise_fma(pr[dx + 0], w2, hv2[0]);
          hv2[1] = __builtin_elementwise_fma(pr[dx + 2], w2, hv2[1]);
          hv2[2] = __builtin_elementwise_fma(pr[dx + 4], w2, hv2[2]);
          hv2[3] = __builtin_elementwise_fma(pr[dx + 6], w2, hv2[3]);
        }
      }
    }

    // ---- LayerNorm over 64 pixels per channel (8 wave-partials, r8 scheme)
    f32x2 ps2 = f32x2{0.f, 0.f}, pq2 = f32x2{0.f, 0.f};
#pragma unroll
    for (int j = 0; j < 4; ++j) {
      ps2 += hv2[j];
      pq2 = __builtin_elementwise_fma(hv2[j], hv2[j], pq2);
    }
    lnred[(wv * 2 + 0) * 64 + lane] = ps2.x + ps2.y;
    lnred[(wv * 2 + 1) * 64 + lane] = pq2.x + pq2.y;
    __syncthreads();  // sync1
    float sm = 0.f, sq = 0.f;
#pragma unroll
    for (int w = 0; w < 8; ++w) {
      sm += lnred[(2 * w + 0) * 64 + lane];
      sq += lnred[(2 * w + 1) * 64 + lane];
    }
    float mu = sm * (1.f / 64.f);
    float var = sq * (1.f / 64.f) - mu * mu;
    float rstd = rsqrtf(var + 1e-5f);
#pragma unroll
    for (int j = 0; j < 8; ++j) {
      int s = wv * 8 + j;  // pixel index owned by this wave
      float hvj = (j & 1) ? hv2[j >> 1].y : hv2[j >> 1].x;
      float nv = (hvj - mu) * rstd * lnw[e * 64 + s] + lnb[e * 64 + s];
      hbf[s * 72 + lane] = f2bf(nv);  // h[px][c] bf16, stride 72
    }
    __syncthreads();  // sync2: h ready

    // ---- pw_in (64->128) MFMA; wave owns A-rows [16wi,+16), G-rows +64,
    //      px-tiles {2jh, 2jh+1}
    const unsigned short* wInE = wInBf + (size_t)e * 8192;
    short8 aA[2], aG[2];
#pragma unroll
    for (int kf = 0; kf < 2; ++kf) {
      aA[kf] = *(const short8*)(wInE + (16 * wi + r15) * 64 + kf * 32 + r4 * 8);
      aG[kf] = *(const short8*)(wInE + (64 + 16 * wi + r15) * 64 + kf * 32 + r4 * 8);
    }
    f32x4 accA[2], accG[2];
#pragma unroll
    for (int ntl = 0; ntl < 2; ++ntl)
#pragma unroll
      for (int v = 0; v < 4; ++v) {
        accA[ntl][v] = pwin_b[e * 128 + 16 * wi + r4 * 4 + v];
        accG[ntl][v] = pwin_b[e * 128 + 64 + 16 * wi + r4 * 4 + v];
      }
#pragma unroll
    for (int ntl = 0; ntl < 2; ++ntl) {
      const int nt = 2 * jh + ntl;
#pragma unroll
      for (int kf = 0; kf < 2; ++kf) {
        short8 bfr = *(const short8*)(hbf + (16 * nt + r15) * 72 + kf * 32 + r4 * 8);
        accA[ntl] = __builtin_amdgcn_mfma_f32_16x16x32_bf16(aA[kf], bfr, accA[ntl], 0, 0, 0);
        accG[ntl] = __builtin_amdgcn_mfma_f32_16x16x32_bf16(aG[kf], bfr, accG[ntl], 0, 0, 0);
      }
    }
    // silu(a)*g -> h3 (separate buffer, packed uint2 = 4 bf16 channels)
#pragma unroll
    for (int ntl = 0; ntl < 2; ++ntl) {
      const int nt = 2 * jh + ntl;
      float hval[4];
#pragma unroll
      for (int v = 0; v < 4; ++v) {
        float a = accA[ntl][v];
        float g = accG[ntl][v];
        hval[v] = __fdividef(a, 1.f + __expf(-a)) * g;
      }
      uint2 w2;
      w2.x = (unsigned)f2bf(hval[0]) | ((unsigned)f2bf(hval[1]) << 16);
      w2.y = (unsigned)f2bf(hval[2]) | ((unsigned)f2bf(hval[3]) << 16);
      *(uint2*)(h3bf + (16 * nt + r15) * 72 + 16 * wi + 4 * r4) = w2;
    }
    __syncthreads();  // sync3: h3 ready

    // ---- pw_out (64->64) MFMA; wave owns rows [16wi,+16), px-tiles {2jh,+1}
    const unsigned short* wOutE = wOutBf + (size_t)e * 4096;
    short8 aO[2];
#pragma unroll
    for (int kf = 0; kf < 2; ++kf)
      aO[kf] = *(const short8*)(wOutE + (16 * wi + r15) * 64 + kf * 32 + r4 * 8);
    f32x4 accO[2];
#pragma unroll
    for (int ntl = 0; ntl < 2; ++ntl)
#pragma unroll
      for (int v = 0; v < 4; ++v) accO[ntl][v] = 0.f;
#pragma unroll
    for (int ntl = 0; ntl < 2; ++ntl) {
      const int nt = 2 * jh + ntl;
#pragma unroll
      for (int kf = 0; kf < 2; ++kf) {
        short8 bfr = *(const short8*)(h3bf + (16 * nt + r15) * 72 + kf * 32 + r4 * 8);
        accO[ntl] = __builtin_amdgcn_mfma_f32_16x16x32_bf16(aO[kf], bfr, accO[ntl], 0, 0, 0);
      }
    }
    float bO[4];
#pragma unroll
    for (int v = 0; v < 4; ++v) bO[v] = pwout_b[e * 64 + 16 * wi + r4 * 4 + v];
#pragma unroll
    for (int ntl = 0; ntl < 2; ++ntl)
#pragma unroll
      for (int v = 0; v < 4; ++v) oacc[ntl * 4 + v] += we * (accO[ntl][v] + bO[v]);
  }

  // ---- epilogue: eb (17408 B) aliases wsdw+hbf+h3bf head; h3bf is read by
  //      pw_out just above -> drain with a barrier before the alias write.
  __syncthreads();  // syncE
#pragma unroll
  for (int ntl = 0; ntl < 2; ++ntl)
#pragma unroll
    for (int v = 0; v < 4; ++v)
      eb[(16 * wi + 4 * r4 + v) * 68 + 16 * (2 * jh + ntl) + r15] = oacc[ntl * 4 + v];
  __syncthreads();
#pragma unroll
  for (int it = 0; it < 2; ++it) {
    int g = it * 512 + t;
    int c = g >> 4, q = g & 15;
    float4 dv = *(const float4*)(eb + c * 68 + q * 4);
    float4 xv;   // residual from global (L2/L3-hot)
    if constexpr (REPACK)
      xv = ((const float4*)xr)[(size_t)bidx * 1024 + g];
    else
      xv = *(const float4*)(x + obase + (size_t)c * 131072 + (q >> 1) * 128 + (q & 1) * 4);
    float4 o4 = {xv.x + dv.x, xv.y + dv.y, xv.z + dv.z, xv.w + dv.w};
    *(float4*)(out + obase + (size_t)c * 131072 + (q >> 1) * 128 + (q & 1) * 4) = o4;
  }
}

extern "C" void kernel_launch(void* const* d_in, const int* in_sizes, int n_in,
                              void* d_out, int out_size, void* d_ws, size_t ws_size,
                              hipStream_t stream) {
  const float* x       = (const float*)d_in[0];
  const float* rw      = (const float*)d_in[1];
  const float* rb      = (const float*)d_in[2];
  const float* dww     = (const float*)d_in[3];
  const float* dwb     = (const float*)d_in[4];
  const float* lnw     = (const float*)d_in[5];
  const float* lnb     = (const float*)d_in[6];
  const float* pwin_w  = (const float*)d_in[7];
  const float* pwin_b  = (const float*)d_in[8];
  const float* pwout_w = (const float*)d_in[9];
  const float* pwout_b = (const float*)d_in[10];
  float* out = (float*)d_out;

  char* ws = (char*)d_ws;
  float*          partial_l = (float*)ws;
  unsigned short* dwTbf     = (unsigned short*)(ws + 1048576);
  int*            sel_i     = (int*)(ws + 1098752);
  float*          sel_w     = (float*)(ws + 1102848);
  unsigned short* wInBf     = (unsigned short*)(ws + 1106944);
  unsigned short* wOutBf    = (unsigned short*)(ws + 1238016);
  float*          xr        = (float*)(ws + 1303552);

  const bool repack = ws_size >= REPACK_NEED;

  hipLaunchKernelGGL(k_pre, dim3(482), dim3(256), 0, stream,
                     dww, pwin_w, pwout_w, dwTbf, wInBf, wOutBf);
  if (repack)
    hipLaunchKernelGGL(k_repack, dim3(2048), dim3(256), 0, stream, x, xr, partial_l);
  else
    hipLaunchKernelGGL(k_sum, dim3(512), dim3(256), 0, stream, x, partial_l);
  hipLaunchKernelGGL(k_router, dim3(512), dim3(64), 0, stream,
                     partial_l, rw, rb, sel_i, sel_w);
  if (repack)
    hipLaunchKernelGGL((k_main<true>), dim3(4096), dim3(512), 0, stream,
                       x, xr, dwTbf, dwb, lnw, lnb, pwin_b, pwout_b,
                       wInBf, wOutBf, sel_i, sel_w, out);
  else
    hipLaunchKernelGGL((k_main<false>), dim3(4096), dim3(512), 0, stream,
                       x, xr, dwTbf, dwb, lnw, lnb, pwin_b, pwout_b,
                       wInBf, wOutBf, sel_i, sel_w, out);
}

// Round 13
// 115.880 us; speedup vs baseline: 1.4192x; 1.2619x over previous
//
#include <hip/hip_runtime.h>
#include <hip/hip_bf16.h>
#include <cstddef>
#include <cstdint>

// SpatialPatchMoE on MI355X (gfx950).
// x[2,64,8,128,128] f32 -> 512 patches x 8 l-slices; router top-2/8;
// per expert: dwconv(1,7,7) -> LN(8,8) -> pw 64->128 -> silu*gate -> pw 64->64;
// out = x + sum_k w_k * expert_k.  Pointwise matmuls = bf16 MFMA 16x16x32.
//
// k_main round 13: BOTH experts fused in one pass (barriers 10 -> 6):
//   conv e0+e1 share x-row unpack; one LN phase; pw phases pipelined over
//   3 rotating h-buffers: {in e0}, {out e0 || in e1}, {out e1 || eb}.
// 512 threads = 8 waves; wave wv owns conv row wv and MFMA row-tile (wv>>1)
// x px-half (wv&1).  NO __launch_bounds__ min-waves (rounds 4-6: min-waves
// cap -> allocator spills 300-500 MB).
//
// LDS carve (49408 B, 3 blocks/CU):
//   wsdw bf16[2][49][64] @0      (12544)
//   B1   u16 [64][72]    @12544  (9216)   h_e0, later h3_e1
//   B2   u16 [64][72]    @21760  (9216)   h_e1, later eb head
//   B3   u16 [64][72]    @30976  (9216)   lnred (8192) then h3_e0
//   xsb  u16 [64][72]    @40192  (9216)
//   eb   f32 [64][68]    @21760  (17408)  epilogue alias over B2+B3
//
// ws layout (bytes):
//   partial_l : f32 [n][l][c]       @ 0         (1048576)
//   dwTbf     : bf16 [e][tap][c]    @ 1048576   (50176)
//   sel_i     : int[2*512]          @ 1098752   (4096)
//   sel_w     : f32[2*512]          @ 1102848   (4096)
//   wInBf     : bf16 [e][128][64]   @ 1106944   (131072)
//   wOutBf    : bf16 [e][64][64]    @ 1238016   (65536)
//   xr        : f32 [n*8+l][c][px]  @ 1303552   (67108864)   (repack path)

typedef __attribute__((ext_vector_type(8))) short short8;
typedef __attribute__((ext_vector_type(4))) float f32x4;
typedef __attribute__((ext_vector_type(2))) float f32x2;

#define REPACK_NEED 68412416ull

__device__ __forceinline__ unsigned short f2bf(float f) {
  return __builtin_bit_cast(unsigned short, __float2bfloat16(f));
}
__device__ __forceinline__ float bflo(unsigned u) {
  return __builtin_bit_cast(float, u << 16);
}
__device__ __forceinline__ float bfhi(unsigned u) {
  return __builtin_bit_cast(float, u & 0xFFFF0000u);
}

__device__ __forceinline__ float wave_sum64(float v) {
#pragma unroll
  for (int m = 32; m > 0; m >>= 1) v += __shfl_xor(v, m, 64);
  return v;
}

// ---------------- preprocess: dw transpose->bf16 + pw weights -> bf16
__global__ void k_pre(const float* __restrict__ dw,
                      const float* __restrict__ pwin,
                      const float* __restrict__ pwout,
                      unsigned short* __restrict__ dwTbf,
                      unsigned short* __restrict__ wIn,
                      unsigned short* __restrict__ wOut) {
  int idx = blockIdx.x * 256 + threadIdx.x;
  if (idx < 25088) {
    int e = idx / 3136;
    int r = idx - e * 3136;
    int c = r / 49;
    int tap = r - c * 49;
    dwTbf[(e * 49 + tap) * 64 + c] = f2bf(dw[idx]);
  } else if (idx < 25088 + 65536) {
    int i = idx - 25088;
    wIn[i] = f2bf(pwin[i]);
  } else if (idx < 25088 + 65536 + 32768) {
    int i = idx - 90624;
    wOut[i] = f2bf(pwout[i]);
  }
}

// ---------------- fallback patch sums (only when ws too small for repack)
__global__ __launch_bounds__(256) void k_sum(const float* __restrict__ x,
                                             float* __restrict__ partial_l) {
  __shared__ float red[256 * 17];
  int t = threadIdx.x, bid = blockIdx.x;
  int b = bid >> 8, c = (bid >> 2) & 63, lp = bid & 3;
  const float4* x4 = (const float4*)x + ((size_t)((b * 64 + c) * 8) + lp * 2) * 4096;
#pragma unroll 1
  for (int l2 = 0; l2 < 2; ++l2) {
    float acc[16];
#pragma unroll
    for (int k = 0; k < 16; ++k) acc[k] = 0.f;
#pragma unroll
    for (int k = 0; k < 16; ++k) {
      float4 v = x4[l2 * 4096 + k * 256 + t];
      acc[k] += v.x + v.y + v.z + v.w;
    }
    int pcol = (t & 31) >> 1;
    int slot = ((t & 1) << 3) | (t >> 5);
    __syncthreads();
#pragma unroll
    for (int k = 0; k < 16; ++k) red[(k * 16 + pcol) * 17 + slot] = acc[k];
    __syncthreads();
    float s = 0.f;
#pragma unroll
    for (int j = 0; j < 16; ++j) s += red[t * 17 + j];
    partial_l[((size_t)(b * 256 + t)) * 512 + (lp * 2 + l2) * 64 + c] = s;
  }
}

// ---------------- repack x -> patch-major xr[(n*8+l)][c][px], fused patch sums
__global__ __launch_bounds__(256) void k_repack(const float* __restrict__ x,
                                                float* __restrict__ xr,
                                                float* __restrict__ partial_l) {
  __shared__ __align__(16) float lt[8 * 1060];
  int t = threadIdx.x, bid = blockIdx.x;
  int ct = bid & 7, hh = (bid >> 3) & 15, l = (bid >> 7) & 7, b = bid >> 10;
  int c0 = ct * 8;
  const float4* x4 = (const float4*)x;
  float4* xr4 = (float4*)xr;
  int y = t >> 5, xq = t & 31;
#pragma unroll
  for (int i = 0; i < 8; ++i) {
    size_t src = ((size_t)((b * 64 + c0 + i) * 8 + l) << 12) +
                 (size_t)(hh * 8 + y) * 32 + xq;
    float4 v = x4[src];
    *(float4*)(lt + i * 1060 + y * 132 + xq * 4) = v;
  }
  __syncthreads();
  int cc = (t >> 4) & 7, ihalf = t >> 7, pxq = t & 15;
  int py = pxq >> 1, xcol = pxq & 1;
#pragma unroll
  for (int iw = 0; iw < 8; ++iw) {
    int ww = ihalf * 8 + iw;
    float4 v = *(const float4*)(lt + cc * 1060 + py * 132 + ww * 8 + xcol * 4);
    int n = b * 256 + hh * 16 + ww;
    xr4[((size_t)(n * 8 + l) << 10) + (c0 + cc) * 16 + pxq] = v;
    float s = v.x + v.y + v.z + v.w;
#pragma unroll
    for (int m = 1; m < 16; m <<= 1) s += __shfl_xor(s, m, 64);
    if (pxq == 0) partial_l[(size_t)(n * 8 + l) * 64 + c0 + cc] = s;
  }
}

// ---------------- router
__global__ void k_router(const float* __restrict__ partial_l,
                         const float* __restrict__ rw, const float* __restrict__ rb,
                         int* __restrict__ sel_i, float* __restrict__ sel_w) {
  int n = blockIdx.x;
  int lane = threadIdx.x;
  float s = 0.f;
#pragma unroll
  for (int l = 0; l < 8; ++l)
    s += partial_l[(size_t)n * 512 + l * 64 + lane];
  float rin = s * (1.f / 512.f);
  float lg[8];
#pragma unroll
  for (int e = 0; e < 8; ++e) {
    float v = rin * rw[e * 64 + lane];
    lg[e] = wave_sum64(v) + rb[e];
  }
  int e0 = 0; float v0 = lg[0];
#pragma unroll
  for (int e = 1; e < 8; ++e) if (lg[e] > v0) { v0 = lg[e]; e0 = e; }
  int e1 = -1; float v1 = -1e30f;
#pragma unroll
  for (int e = 0; e < 8; ++e) if (e != e0 && lg[e] > v1) { v1 = lg[e]; e1 = e; }
  if (lane == 0) {
    float w1 = __expf(v1 - v0);
    float z = 1.f + w1;
    sel_i[2 * n] = e0; sel_i[2 * n + 1] = e1;
    sel_w[2 * n] = 1.f / z; sel_w[2 * n + 1] = w1 / z;
  }
}

// ---------------- main: one block per (patch n, depth l); 8 waves of 64
template <bool REPACK>
__global__ __launch_bounds__(512) void k_main(
    const float* __restrict__ x, const float* __restrict__ xr,
    const unsigned short* __restrict__ dwTbf, const float* __restrict__ dwb,
    const float* __restrict__ lnw, const float* __restrict__ lnb,
    const float* __restrict__ pwin_b, const float* __restrict__ pwout_b,
    const unsigned short* __restrict__ wInBf,
    const unsigned short* __restrict__ wOutBf,
    const int* __restrict__ sel_i, const float* __restrict__ sel_w,
    float* __restrict__ out) {
  __shared__ __align__(16) char smem[49408];
  unsigned short* wsdw = (unsigned short*)smem;            // [2][49][64] bf16
  unsigned short* B1   = (unsigned short*)(smem + 12544);  // h_e0 -> h3_e1
  unsigned short* B2   = (unsigned short*)(smem + 21760);  // h_e1 -> (eb head)
  unsigned short* B3   = (unsigned short*)(smem + 30976);  // lnred -> h3_e0
  float* lnred         = (float*)(smem + 30976);
  unsigned short* xsb  = (unsigned short*)(smem + 40192);
  float* eb            = (float*)(smem + 21760);           // alias B2+B3

  const int t = threadIdx.x;
  const int lane = t & 63;
  const int wv = __builtin_amdgcn_readfirstlane(t >> 6);  // 0..7
  const int wi = wv >> 1;      // MFMA row-tile index 0..3
  const int jh = wv & 1;       // px-half 0..1
  const int r15 = lane & 15, r4 = lane >> 4;
  const int bidx = blockIdx.x;
  const int n = bidx >> 3, l = bidx & 7;
  const int b = n >> 8, p = n & 255;
  const int hh = p >> 4, ww = p & 15;
  const size_t obase = (size_t)b * 8388608 + (size_t)l * 16384 +
                       (size_t)hh * 1024 + (size_t)ww * 8;

  const int e0 = __builtin_amdgcn_readfirstlane(sel_i[2 * n]);
  const int e1 = __builtin_amdgcn_readfirstlane(sel_i[2 * n + 1]);
  const float we0 = sel_w[2 * n];
  const float we1 = sel_w[2 * n + 1];

  // ---- phase 0: stage x slice -> xsb bf16 (stride 72, XOR row swizzle) and
  //      BOTH experts' dw weights (784 uint4 linear: [0,392)=e0, [392,784)=e1)
#pragma unroll
  for (int it = 0; it < 2; ++it) {
    int g = it * 512 + t;
    int c = g >> 4, q = g & 15;
    float4 v;
    if constexpr (REPACK)
      v = ((const float4*)xr)[(size_t)bidx * 1024 + g];
    else
      v = *(const float4*)(x + obase + (size_t)c * 131072 + (q >> 1) * 128 + (q & 1) * 4);
    int rs = (q >> 1) ^ ((c >> 3) & 7);
    uint2 w2;
    w2.x = (unsigned)f2bf(v.x) | ((unsigned)f2bf(v.y) << 16);
    w2.y = (unsigned)f2bf(v.z) | ((unsigned)f2bf(v.w) << 16);
    *(uint2*)(xsb + c * 72 + rs * 8 + (q & 1) * 4) = w2;
  }
  {
    uint4* dst = (uint4*)wsdw;
    const uint4* s0 = (const uint4*)(dwTbf + (size_t)e0 * 3136);
    const uint4* s1 = (const uint4*)(dwTbf + (size_t)e1 * 3136);
    if (t < 392) dst[t] = s0[t];
    else dst[t] = s1[t - 392];          // e1[0..120)
    if (t < 272) dst[512 + t] = s1[120 + t];  // e1[120..392)
  }
  __syncthreads();  // barrier A

  // ---- phase 1: conv BOTH experts; shared x unpack; wave wv owns row wv
  f32x2 hva[4], hvb[4];
  {
    const float bias0 = dwb[e0 * 64 + lane];
    const float bias1 = dwb[e1 * 64 + lane];
#pragma unroll
    for (int j = 0; j < 4; ++j) {
      hva[j] = f32x2{bias0, bias0};
      hvb[j] = f32x2{bias1, bias1};
    }
  }
  {
    const unsigned short* rowbase = xsb + lane * 72;
    const int rc = (lane >> 3) & 7;
    const unsigned short* wl0 = wsdw + lane;
    const unsigned short* wl1 = wsdw + 3136 + lane;
    const int y0 = wv;
    const int rlo = (y0 - 3 < 0) ? 0 : y0 - 3;
    const int rhi = (y0 + 3 > 7) ? 7 : y0 + 3;
    for (int r = rlo; r <= rhi; ++r) {   // runtime loop: small code, few regs
      uint4 xraw = *(const uint4*)(rowbase + (r ^ rc) * 8);
      float xp[14];
      xp[0] = 0.f; xp[1] = 0.f; xp[2] = 0.f;
      xp[3] = bflo(xraw.x); xp[4] = bfhi(xraw.x);
      xp[5] = bflo(xraw.y); xp[6] = bfhi(xraw.y);
      xp[7] = bflo(xraw.z); xp[8] = bfhi(xraw.z);
      xp[9] = bflo(xraw.w); xp[10] = bfhi(xraw.w);
      xp[11] = 0.f; xp[12] = 0.f; xp[13] = 0.f;
      f32x2 pr[13];
#pragma unroll
      for (int m = 0; m < 13; ++m) pr[m] = f32x2{xp[m], xp[m + 1]};
      const int roff = (r - y0 + 3) * 448;
      const unsigned short* wrow0 = wl0 + roff;
      const unsigned short* wrow1 = wl1 + roff;
#pragma unroll
      for (int dx = 0; dx < 7; ++dx) {
        float wt0 = bflo((unsigned)wrow0[dx * 64]);
        float wt1 = bflo((unsigned)wrow1[dx * 64]);
        f32x2 w20 = f32x2{wt0, wt0};
        f32x2 w21 = f32x2{wt1, wt1};
        hva[0] = __builtin_elementwise_fma(pr[dx + 0], w20, hva[0]);
        hva[1] = __builtin_elementwise_fma(pr[dx + 2], w20, hva[1]);
        hva[2] = __builtin_elementwise_fma(pr[dx + 4], w20, hva[2]);
        hva[3] = __builtin_elementwise_fma(pr[dx + 6], w20, hva[3]);
        hvb[0] = __builtin_elementwise_fma(pr[dx + 0], w21, hvb[0]);
        hvb[1] = __builtin_elementwise_fma(pr[dx + 2], w21, hvb[1]);
        hvb[2] = __builtin_elementwise_fma(pr[dx + 4], w21, hvb[2]);
        hvb[3] = __builtin_elementwise_fma(pr[dx + 6], w21, hvb[3]);
      }
    }
  }
  // LN partials for both experts -> lnred[k][wv*2+s][lane] (aliases B3)
  {
    f32x2 psa = f32x2{0.f, 0.f}, pqa = f32x2{0.f, 0.f};
    f32x2 psb = f32x2{0.f, 0.f}, pqb = f32x2{0.f, 0.f};
#pragma unroll
    for (int j = 0; j < 4; ++j) {
      psa += hva[j];
      pqa = __builtin_elementwise_fma(hva[j], hva[j], pqa);
      psb += hvb[j];
      pqb = __builtin_elementwise_fma(hvb[j], hvb[j], pqb);
    }
    lnred[(wv * 2 + 0) * 64 + lane] = psa.x + psa.y;
    lnred[(wv * 2 + 1) * 64 + lane] = pqa.x + pqa.y;
    lnred[1024 + (wv * 2 + 0) * 64 + lane] = psb.x + psb.y;
    lnred[1024 + (wv * 2 + 1) * 64 + lane] = pqb.x + pqb.y;
  }
  __syncthreads();  // barrier B

  // ---- phase 2: LN finalize both; h_e0 -> B1, h_e1 -> B2
  {
    float sm0 = 0.f, sq0 = 0.f, sm1 = 0.f, sq1 = 0.f;
#pragma unroll
    for (int w = 0; w < 8; ++w) {
      sm0 += lnred[(2 * w + 0) * 64 + lane];
      sq0 += lnred[(2 * w + 1) * 64 + lane];
      sm1 += lnred[1024 + (2 * w + 0) * 64 + lane];
      sq1 += lnred[1024 + (2 * w + 1) * 64 + lane];
    }
    float mu0 = sm0 * (1.f / 64.f);
    float rstd0 = rsqrtf(sq0 * (1.f / 64.f) - mu0 * mu0 + 1e-5f);
    float mu1 = sm1 * (1.f / 64.f);
    float rstd1 = rsqrtf(sq1 * (1.f / 64.f) - mu1 * mu1 + 1e-5f);
#pragma unroll
    for (int j = 0; j < 8; ++j) {
      int s = wv * 8 + j;
      float ha = (j & 1) ? hva[j >> 1].y : hva[j >> 1].x;
      float hb = (j & 1) ? hvb[j >> 1].y : hvb[j >> 1].x;
      float nv0 = (ha - mu0) * rstd0 * lnw[e0 * 64 + s] + lnb[e0 * 64 + s];
      float nv1 = (hb - mu1) * rstd1 * lnw[e1 * 64 + s] + lnb[e1 * 64 + s];
      B1[s * 72 + lane] = f2bf(nv0);
      B2[s * 72 + lane] = f2bf(nv1);
    }
  }
  __syncthreads();  // barrier C (also: lnred reads done before B3 reused)

  float oacc[8];
#pragma unroll
  for (int i = 0; i < 8; ++i) oacc[i] = 0.f;

  // ---- phase 3: pw_in e0 (read B1) -> silu -> h3_e0 into B3
  {
    const unsigned short* wInE = wInBf + (size_t)e0 * 8192;
    short8 aA[2], aG[2];
#pragma unroll
    for (int kf = 0; kf < 2; ++kf) {
      aA[kf] = *(const short8*)(wInE + (16 * wi + r15) * 64 + kf * 32 + r4 * 8);
      aG[kf] = *(const short8*)(wInE + (64 + 16 * wi + r15) * 64 + kf * 32 + r4 * 8);
    }
    f32x4 accA[2], accG[2];
#pragma unroll
    for (int ntl = 0; ntl < 2; ++ntl)
#pragma unroll
      for (int v = 0; v < 4; ++v) {
        accA[ntl][v] = pwin_b[e0 * 128 + 16 * wi + r4 * 4 + v];
        accG[ntl][v] = pwin_b[e0 * 128 + 64 + 16 * wi + r4 * 4 + v];
      }
#pragma unroll
    for (int ntl = 0; ntl < 2; ++ntl) {
      const int nt = 2 * jh + ntl;
#pragma unroll
      for (int kf = 0; kf < 2; ++kf) {
        short8 bfr = *(const short8*)(B1 + (16 * nt + r15) * 72 + kf * 32 + r4 * 8);
        accA[ntl] = __builtin_amdgcn_mfma_f32_16x16x32_bf16(aA[kf], bfr, accA[ntl], 0, 0, 0);
        accG[ntl] = __builtin_amdgcn_mfma_f32_16x16x32_bf16(aG[kf], bfr, accG[ntl], 0, 0, 0);
      }
    }
#pragma unroll
    for (int ntl = 0; ntl < 2; ++ntl) {
      const int nt = 2 * jh + ntl;
      float hval[4];
#pragma unroll
      for (int v = 0; v < 4; ++v) {
        float a = accA[ntl][v];
        float g = accG[ntl][v];
        hval[v] = __fdividef(a, 1.f + __expf(-a)) * g;
      }
      uint2 w2;
      w2.x = (unsigned)f2bf(hval[0]) | ((unsigned)f2bf(hval[1]) << 16);
      w2.y = (unsigned)f2bf(hval[2]) | ((unsigned)f2bf(hval[3]) << 16);
      *(uint2*)(B3 + (16 * nt + r15) * 72 + 16 * wi + 4 * r4) = w2;
    }
  }
  __syncthreads();  // barrier D (h3_e0 ready; all B1 reads done)

  // ---- phase 4: pw_out e0 (read B3) -> oacc  ||  pw_in e1 (read B2) -> B1
  {
    const unsigned short* wOutE = wOutBf + (size_t)e0 * 4096;
    short8 aO[2];
#pragma unroll
    for (int kf = 0; kf < 2; ++kf)
      aO[kf] = *(const short8*)(wOutE + (16 * wi + r15) * 64 + kf * 32 + r4 * 8);
    f32x4 accO[2];
#pragma unroll
    for (int ntl = 0; ntl < 2; ++ntl)
#pragma unroll
      for (int v = 0; v < 4; ++v) accO[ntl][v] = 0.f;
#pragma unroll
    for (int ntl = 0; ntl < 2; ++ntl) {
      const int nt = 2 * jh + ntl;
#pragma unroll
      for (int kf = 0; kf < 2; ++kf) {
        short8 bfr = *(const short8*)(B3 + (16 * nt + r15) * 72 + kf * 32 + r4 * 8);
        accO[ntl] = __builtin_amdgcn_mfma_f32_16x16x32_bf16(aO[kf], bfr, accO[ntl], 0, 0, 0);
      }
    }
    float bO[4];
#pragma unroll
    for (int v = 0; v < 4; ++v) bO[v] = pwout_b[e0 * 64 + 16 * wi + r4 * 4 + v];
#pragma unroll
    for (int ntl = 0; ntl < 2; ++ntl)
#pragma unroll
      for (int v = 0; v < 4; ++v) oacc[ntl * 4 + v] += we0 * (accO[ntl][v] + bO[v]);

    // pw_in e1
    const unsigned short* wInE = wInBf + (size_t)e1 * 8192;
    short8 aA[2], aG[2];
#pragma unroll
    for (int kf = 0; kf < 2; ++kf) {
      aA[kf] = *(const short8*)(wInE + (16 * wi + r15) * 64 + kf * 32 + r4 * 8);
      aG[kf] = *(const short8*)(wInE + (64 + 16 * wi + r15) * 64 + kf * 32 + r4 * 8);
    }
    f32x4 accA[2], accG[2];
#pragma unroll
    for (int ntl = 0; ntl < 2; ++ntl)
#pragma unroll
      for (int v = 0; v < 4; ++v) {
        accA[ntl][v] = pwin_b[e1 * 128 + 16 * wi + r4 * 4 + v];
        accG[ntl][v] = pwin_b[e1 * 128 + 64 + 16 * wi + r4 * 4 + v];
      }
#pragma unroll
    for (int ntl = 0; ntl < 2; ++ntl) {
      const int nt = 2 * jh + ntl;
#pragma unroll
      for (int kf = 0; kf < 2; ++kf) {
        short8 bfr = *(const short8*)(B2 + (16 * nt + r15) * 72 + kf * 32 + r4 * 8);
        accA[ntl] = __builtin_amdgcn_mfma_f32_16x16x32_bf16(aA[kf], bfr, accA[ntl], 0, 0, 0);
        accG[ntl] = __builtin_amdgcn_mfma_f32_16x16x32_bf16(aG[kf], bfr, accG[ntl], 0, 0, 0);
      }
    }
#pragma unroll
    for (int ntl = 0; ntl < 2; ++ntl) {
      const int nt = 2 * jh + ntl;
      float hval[4];
#pragma unroll
      for (int v = 0; v < 4; ++v) {
        float a = accA[ntl][v];
        float g = accG[ntl][v];
        hval[v] = __fdividef(a, 1.f + __expf(-a)) * g;
      }
      uint2 w2;
      w2.x = (unsigned)f2bf(hval[0]) | ((unsigned)f2bf(hval[1]) << 16);
      w2.y = (unsigned)f2bf(hval[2]) | ((unsigned)f2bf(hval[3]) << 16);
      *(uint2*)(B1 + (16 * nt + r15) * 72 + 16 * wi + 4 * r4) = w2;  // h3_e1
    }
  }
  __syncthreads();  // barrier E (h3_e1 ready; B2/B3 reads done -> eb writable)

  // ---- phase 5: pw_out e1 (read B1) -> oacc; write eb (aliases B2+B3)
  {
    const unsigned short* wOutE = wOutBf + (size_t)e1 * 4096;
    short8 aO[2];
#pragma unroll
    for (int kf = 0; kf < 2; ++kf)
      aO[kf] = *(const short8*)(wOutE + (16 * wi + r15) * 64 + kf * 32 + r4 * 8);
    f32x4 accO[2];
#pragma unroll
    for (int ntl = 0; ntl < 2; ++ntl)
#pragma unroll
      for (int v = 0; v < 4; ++v) accO[ntl][v] = 0.f;
#pragma unroll
    for (int ntl = 0; ntl < 2; ++ntl) {
      const int nt = 2 * jh + ntl;
#pragma unroll
      for (int kf = 0; kf < 2; ++kf) {
        short8 bfr = *(const short8*)(B1 + (16 * nt + r15) * 72 + kf * 32 + r4 * 8);
        accO[ntl] = __builtin_amdgcn_mfma_f32_16x16x32_bf16(aO[kf], bfr, accO[ntl], 0, 0, 0);
      }
    }
    float bO[4];
#pragma unroll
    for (int v = 0; v < 4; ++v) bO[v] = pwout_b[e1 * 64 + 16 * wi + r4 * 4 + v];
#pragma unroll
    for (int ntl = 0; ntl < 2; ++ntl)
#pragma unroll
      for (int v = 0; v < 4; ++v) oacc[ntl * 4 + v] += we1 * (accO[ntl][v] + bO[v]);
  }
#pragma unroll
  for (int ntl = 0; ntl < 2; ++ntl)
#pragma unroll
    for (int v = 0; v < 4; ++v)
      eb[(16 * wi + 4 * r4 + v) * 68 + 16 * (2 * jh + ntl) + r15] = oacc[ntl * 4 + v];
  __syncthreads();  // barrier F

  // ---- epilogue: read eb, residual from global, store
#pragma unroll
  for (int it = 0; it < 2; ++it) {
    int g = it * 512 + t;
    int c = g >> 4, q = g & 15;
    float4 dv = *(const float4*)(eb + c * 68 + q * 4);
    float4 xv;   // residual from global (L2/L3-hot)
    if constexpr (REPACK)
      xv = ((const float4*)xr)[(size_t)bidx * 1024 + g];
    else
      xv = *(const float4*)(x + obase + (size_t)c * 131072 + (q >> 1) * 128 + (q & 1) * 4);
    float4 o4 = {xv.x + dv.x, xv.y + dv.y, xv.z + dv.z, xv.w + dv.w};
    *(float4*)(out + obase + (size_t)c * 131072 + (q >> 1) * 128 + (q & 1) * 4) = o4;
  }
}

extern "C" void kernel_launch(void* const* d_in, const int* in_sizes, int n_in,
                              void* d_out, int out_size, void* d_ws, size_t ws_size,
                              hipStream_t stream) {
  const float* x       = (const float*)d_in[0];
  const float* rw      = (const float*)d_in[1];
  const float* rb      = (const float*)d_in[2];
  const float* dww     = (const float*)d_in[3];
  const float* dwb     = (const float*)d_in[4];
  const float* lnw     = (const float*)d_in[5];
  const float* lnb     = (const float*)d_in[6];
  const float* pwin_w  = (const float*)d_in[7];
  const float* pwin_b  = (const float*)d_in[8];
  const float* pwout_w = (const float*)d_in[9];
  const float* pwout_b = (const float*)d_in[10];
  float* out = (float*)d_out;

  char* ws = (char*)d_ws;
  float*          partial_l = (float*)ws;
  unsigned short* dwTbf     = (unsigned short*)(ws + 1048576);
  int*            sel_i     = (int*)(ws + 1098752);
  float*          sel_w     = (float*)(ws + 1102848);
  unsigned short* wInBf     = (unsigned short*)(ws + 1106944);
  unsigned short* wOutBf    = (unsigned short*)(ws + 1238016);
  float*          xr        = (float*)(ws + 1303552);

  const bool repack = ws_size >= REPACK_NEED;

  hipLaunchKernelGGL(k_pre, dim3(482), dim3(256), 0, stream,
                     dww, pwin_w, pwout_w, dwTbf, wInBf, wOutBf);
  if (repack)
    hipLaunchKernelGGL(k_repack, dim3(2048), dim3(256), 0, stream, x, xr, partial_l);
  else
    hipLaunchKernelGGL(k_sum, dim3(512), dim3(256), 0, stream, x, partial_l);
  hipLaunchKernelGGL(k_router, dim3(512), dim3(64), 0, stream,
                     partial_l, rw, rb, sel_i, sel_w);
  if (repack)
    hipLaunchKernelGGL((k_main<true>), dim3(4096), dim3(512), 0, stream,
                       x, xr, dwTbf, dwb, lnw, lnb, pwin_b, pwout_b,
                       wInBf, wOutBf, sel_i, sel_w, out);
  else
    hipLaunchKernelGGL((k_main<false>), dim3(4096), dim3(512), 0, stream,
                       x, xr, dwTbf, dwb, lnw, lnb, pwin_b, pwout_b,
                       wInBf, wOutBf, sel_i, sel_w, out);
}

// Round 14
// 114.236 us; speedup vs baseline: 1.4396x; 1.0144x over previous
//
#include <hip/hip_runtime.h>
#include <hip/hip_bf16.h>
#include <cstddef>
#include <cstdint>

// SpatialPatchMoE on MI355X (gfx950).
// x[2,64,8,128,128] f32 -> 512 patches x 8 l-slices; router top-2/8;
// per expert: dwconv(1,7,7) -> LN(8,8) -> pw 64->128 -> silu*gate -> pw 64->64;
// out = x + sum_k w_k * expert_k.  Pointwise matmuls = bf16 MFMA 16x16x32.
//
// k_main round 14 = round 13 (fused two-expert pass, 6 barriers) with LDS-pipe
// cuts: (a) conv weights packed e0|e1 in one u32 -> 7 ds_read_b32 per row
// instead of 14 ds_read_u16; (b) LN partials packed f32x2 -> b64 LDS ops.
//
// LDS carve (49408 B, 3 blocks/CU):
//   wsdw u32[49][64] (e0 lo | e1 hi) @0      (12544)
//   B1   u16 [64][72]    @12544  (9216)   h_e0, later h3_e1
//   B2   u16 [64][72]    @21760  (9216)   h_e1, later eb head
//   B3   u16 [64][72]    @30976  (9216)   lnred f32x2 (8192) then h3_e0
//   xsb  u16 [64][72]    @40192  (9216)
//   eb   f32 [64][68]    @21760  (17408)  epilogue alias over B2+B3
//
// ws layout (bytes):
//   partial_l : f32 [n][l][c]       @ 0         (1048576)
//   dwTbf     : bf16 [e][tap][c]    @ 1048576   (50176)
//   sel_i     : int[2*512]          @ 1098752   (4096)
//   sel_w     : f32[2*512]          @ 1102848   (4096)
//   wInBf     : bf16 [e][128][64]   @ 1106944   (131072)
//   wOutBf    : bf16 [e][64][64]    @ 1238016   (65536)
//   xr        : f32 [n*8+l][c][px]  @ 1303552   (67108864)   (repack path)

typedef __attribute__((ext_vector_type(8))) short short8;
typedef __attribute__((ext_vector_type(4))) float f32x4;
typedef __attribute__((ext_vector_type(2))) float f32x2;

#define REPACK_NEED 68412416ull

__device__ __forceinline__ unsigned short f2bf(float f) {
  return __builtin_bit_cast(unsigned short, __float2bfloat16(f));
}
__device__ __forceinline__ float bflo(unsigned u) {
  return __builtin_bit_cast(float, u << 16);
}
__device__ __forceinline__ float bfhi(unsigned u) {
  return __builtin_bit_cast(float, u & 0xFFFF0000u);
}

__device__ __forceinline__ float wave_sum64(float v) {
#pragma unroll
  for (int m = 32; m > 0; m >>= 1) v += __shfl_xor(v, m, 64);
  return v;
}

// ---------------- preprocess: dw transpose->bf16 + pw weights -> bf16
__global__ void k_pre(const float* __restrict__ dw,
                      const float* __restrict__ pwin,
                      const float* __restrict__ pwout,
                      unsigned short* __restrict__ dwTbf,
                      unsigned short* __restrict__ wIn,
                      unsigned short* __restrict__ wOut) {
  int idx = blockIdx.x * 256 + threadIdx.x;
  if (idx < 25088) {
    int e = idx / 3136;
    int r = idx - e * 3136;
    int c = r / 49;
    int tap = r - c * 49;
    dwTbf[(e * 49 + tap) * 64 + c] = f2bf(dw[idx]);
  } else if (idx < 25088 + 65536) {
    int i = idx - 25088;
    wIn[i] = f2bf(pwin[i]);
  } else if (idx < 25088 + 65536 + 32768) {
    int i = idx - 90624;
    wOut[i] = f2bf(pwout[i]);
  }
}

// ---------------- fallback patch sums (only when ws too small for repack)
__global__ __launch_bounds__(256) void k_sum(const float* __restrict__ x,
                                             float* __restrict__ partial_l) {
  __shared__ float red[256 * 17];
  int t = threadIdx.x, bid = blockIdx.x;
  int b = bid >> 8, c = (bid >> 2) & 63, lp = bid & 3;
  const float4* x4 = (const float4*)x + ((size_t)((b * 64 + c) * 8) + lp * 2) * 4096;
#pragma unroll 1
  for (int l2 = 0; l2 < 2; ++l2) {
    float acc[16];
#pragma unroll
    for (int k = 0; k < 16; ++k) acc[k] = 0.f;
#pragma unroll
    for (int k = 0; k < 16; ++k) {
      float4 v = x4[l2 * 4096 + k * 256 + t];
      acc[k] += v.x + v.y + v.z + v.w;
    }
    int pcol = (t & 31) >> 1;
    int slot = ((t & 1) << 3) | (t >> 5);
    __syncthreads();
#pragma unroll
    for (int k = 0; k < 16; ++k) red[(k * 16 + pcol) * 17 + slot] = acc[k];
    __syncthreads();
    float s = 0.f;
#pragma unroll
    for (int j = 0; j < 16; ++j) s += red[t * 17 + j];
    partial_l[((size_t)(b * 256 + t)) * 512 + (lp * 2 + l2) * 64 + c] = s;
  }
}

// ---------------- repack x -> patch-major xr[(n*8+l)][c][px], fused patch sums
__global__ __launch_bounds__(256) void k_repack(const float* __restrict__ x,
                                                float* __restrict__ xr,
                                                float* __restrict__ partial_l) {
  __shared__ __align__(16) float lt[8 * 1060];
  int t = threadIdx.x, bid = blockIdx.x;
  int ct = bid & 7, hh = (bid >> 3) & 15, l = (bid >> 7) & 7, b = bid >> 10;
  int c0 = ct * 8;
  const float4* x4 = (const float4*)x;
  float4* xr4 = (float4*)xr;
  int y = t >> 5, xq = t & 31;
#pragma unroll
  for (int i = 0; i < 8; ++i) {
    size_t src = ((size_t)((b * 64 + c0 + i) * 8 + l) << 12) +
                 (size_t)(hh * 8 + y) * 32 + xq;
    float4 v = x4[src];
    *(float4*)(lt + i * 1060 + y * 132 + xq * 4) = v;
  }
  __syncthreads();
  int cc = (t >> 4) & 7, ihalf = t >> 7, pxq = t & 15;
  int py = pxq >> 1, xcol = pxq & 1;
#pragma unroll
  for (int iw = 0; iw < 8; ++iw) {
    int ww = ihalf * 8 + iw;
    float4 v = *(const float4*)(lt + cc * 1060 + py * 132 + ww * 8 + xcol * 4);
    int n = b * 256 + hh * 16 + ww;
    xr4[((size_t)(n * 8 + l) << 10) + (c0 + cc) * 16 + pxq] = v;
    float s = v.x + v.y + v.z + v.w;
#pragma unroll
    for (int m = 1; m < 16; m <<= 1) s += __shfl_xor(s, m, 64);
    if (pxq == 0) partial_l[(size_t)(n * 8 + l) * 64 + c0 + cc] = s;
  }
}

// ---------------- router
__global__ void k_router(const float* __restrict__ partial_l,
                         const float* __restrict__ rw, const float* __restrict__ rb,
                         int* __restrict__ sel_i, float* __restrict__ sel_w) {
  int n = blockIdx.x;
  int lane = threadIdx.x;
  float s = 0.f;
#pragma unroll
  for (int l = 0; l < 8; ++l)
    s += partial_l[(size_t)n * 512 + l * 64 + lane];
  float rin = s * (1.f / 512.f);
  float lg[8];
#pragma unroll
  for (int e = 0; e < 8; ++e) {
    float v = rin * rw[e * 64 + lane];
    lg[e] = wave_sum64(v) + rb[e];
  }
  int e0 = 0; float v0 = lg[0];
#pragma unroll
  for (int e = 1; e < 8; ++e) if (lg[e] > v0) { v0 = lg[e]; e0 = e; }
  int e1 = -1; float v1 = -1e30f;
#pragma unroll
  for (int e = 0; e < 8; ++e) if (e != e0 && lg[e] > v1) { v1 = lg[e]; e1 = e; }
  if (lane == 0) {
    float w1 = __expf(v1 - v0);
    float z = 1.f + w1;
    sel_i[2 * n] = e0; sel_i[2 * n + 1] = e1;
    sel_w[2 * n] = 1.f / z; sel_w[2 * n + 1] = w1 / z;
  }
}

// ---------------- main: one block per (patch n, depth l); 8 waves of 64
template <bool REPACK>
__global__ __launch_bounds__(512) void k_main(
    const float* __restrict__ x, const float* __restrict__ xr,
    const unsigned short* __restrict__ dwTbf, const float* __restrict__ dwb,
    const float* __restrict__ lnw, const float* __restrict__ lnb,
    const float* __restrict__ pwin_b, const float* __restrict__ pwout_b,
    const unsigned short* __restrict__ wInBf,
    const unsigned short* __restrict__ wOutBf,
    const int* __restrict__ sel_i, const float* __restrict__ sel_w,
    float* __restrict__ out) {
  __shared__ __align__(16) char smem[49408];
  unsigned* wsdw       = (unsigned*)smem;                  // [49][64] u32 e0|e1
  unsigned short* B1   = (unsigned short*)(smem + 12544);  // h_e0 -> h3_e1
  unsigned short* B2   = (unsigned short*)(smem + 21760);  // h_e1 -> (eb head)
  unsigned short* B3   = (unsigned short*)(smem + 30976);  // lnred -> h3_e0
  f32x2* ln2           = (f32x2*)(smem + 30976);           // [2][8][64] f32x2
  unsigned short* xsb  = (unsigned short*)(smem + 40192);
  float* eb            = (float*)(smem + 21760);           // alias B2+B3

  const int t = threadIdx.x;
  const int lane = t & 63;
  const int wv = __builtin_amdgcn_readfirstlane(t >> 6);  // 0..7
  const int wi = wv >> 1;      // MFMA row-tile index 0..3
  const int jh = wv & 1;       // px-half 0..1
  const int r15 = lane & 15, r4 = lane >> 4;
  const int bidx = blockIdx.x;
  const int n = bidx >> 3, l = bidx & 7;
  const int b = n >> 8, p = n & 255;
  const int hh = p >> 4, ww = p & 15;
  const size_t obase = (size_t)b * 8388608 + (size_t)l * 16384 +
                       (size_t)hh * 1024 + (size_t)ww * 8;

  const int e0 = __builtin_amdgcn_readfirstlane(sel_i[2 * n]);
  const int e1 = __builtin_amdgcn_readfirstlane(sel_i[2 * n + 1]);
  const float we0 = sel_w[2 * n];
  const float we1 = sel_w[2 * n + 1];

  // ---- phase 0: stage x slice -> xsb bf16 (stride 72, XOR row swizzle) and
  //      both experts' dw weights packed u32 (lo = e0, hi = e1)
#pragma unroll
  for (int it = 0; it < 2; ++it) {
    int g = it * 512 + t;
    int c = g >> 4, q = g & 15;
    float4 v;
    if constexpr (REPACK)
      v = ((const float4*)xr)[(size_t)bidx * 1024 + g];
    else
      v = *(const float4*)(x + obase + (size_t)c * 131072 + (q >> 1) * 128 + (q & 1) * 4);
    int rs = (q >> 1) ^ ((c >> 3) & 7);
    uint2 w2;
    w2.x = (unsigned)f2bf(v.x) | ((unsigned)f2bf(v.y) << 16);
    w2.y = (unsigned)f2bf(v.z) | ((unsigned)f2bf(v.w) << 16);
    *(uint2*)(xsb + c * 72 + rs * 8 + (q & 1) * 4) = w2;
  }
  {
    const unsigned short* s0 = dwTbf + (size_t)e0 * 3136;
    const unsigned short* s1 = dwTbf + (size_t)e1 * 3136;
#pragma unroll
    for (int i = 0; i < 6; ++i) {
      int idx = i * 512 + t;
      wsdw[idx] = (unsigned)s0[idx] | ((unsigned)s1[idx] << 16);
    }
    if (t < 64) wsdw[3072 + t] = (unsigned)s0[3072 + t] | ((unsigned)s1[3072 + t] << 16);
  }
  __syncthreads();  // barrier A

  // ---- phase 1: conv BOTH experts; shared x unpack; wave wv owns row wv
  f32x2 hva[4], hvb[4];
  {
    const float bias0 = dwb[e0 * 64 + lane];
    const float bias1 = dwb[e1 * 64 + lane];
#pragma unroll
    for (int j = 0; j < 4; ++j) {
      hva[j] = f32x2{bias0, bias0};
      hvb[j] = f32x2{bias1, bias1};
    }
  }
  {
    const unsigned short* rowbase = xsb + lane * 72;
    const int rc = (lane >> 3) & 7;
    const unsigned* wl = wsdw + lane;
    const int y0 = wv;
    const int rlo = (y0 - 3 < 0) ? 0 : y0 - 3;
    const int rhi = (y0 + 3 > 7) ? 7 : y0 + 3;
    for (int r = rlo; r <= rhi; ++r) {   // runtime loop: small code, few regs
      uint4 xraw = *(const uint4*)(rowbase + (r ^ rc) * 8);
      float xp[14];
      xp[0] = 0.f; xp[1] = 0.f; xp[2] = 0.f;
      xp[3] = bflo(xraw.x); xp[4] = bfhi(xraw.x);
      xp[5] = bflo(xraw.y); xp[6] = bfhi(xraw.y);
      xp[7] = bflo(xraw.z); xp[8] = bfhi(xraw.z);
      xp[9] = bflo(xraw.w); xp[10] = bfhi(xraw.w);
      xp[11] = 0.f; xp[12] = 0.f; xp[13] = 0.f;
      f32x2 pr[13];
#pragma unroll
      for (int m = 0; m < 13; ++m) pr[m] = f32x2{xp[m], xp[m + 1]};
      const unsigned* wrow = wl + (r - y0 + 3) * 448;   // 7 taps * 64 u32
#pragma unroll
      for (int dx = 0; dx < 7; ++dx) {
        unsigned wp = wrow[dx * 64];        // one ds_read_b32, both experts
        float wt0 = bflo(wp);
        float wt1 = bfhi(wp);
        f32x2 w20 = f32x2{wt0, wt0};
        f32x2 w21 = f32x2{wt1, wt1};
        hva[0] = __builtin_elementwise_fma(pr[dx + 0], w20, hva[0]);
        hva[1] = __builtin_elementwise_fma(pr[dx + 2], w20, hva[1]);
        hva[2] = __builtin_elementwise_fma(pr[dx + 4], w20, hva[2]);
        hva[3] = __builtin_elementwise_fma(pr[dx + 6], w20, hva[3]);
        hvb[0] = __builtin_elementwise_fma(pr[dx + 0], w21, hvb[0]);
        hvb[1] = __builtin_elementwise_fma(pr[dx + 2], w21, hvb[1]);
        hvb[2] = __builtin_elementwise_fma(pr[dx + 4], w21, hvb[2]);
        hvb[3] = __builtin_elementwise_fma(pr[dx + 6], w21, hvb[3]);
      }
    }
  }
  // LN partials for both experts, packed f32x2 -> ln2 (aliases B3)
  {
    f32x2 psa = f32x2{0.f, 0.f}, pqa = f32x2{0.f, 0.f};
    f32x2 psb = f32x2{0.f, 0.f}, pqb = f32x2{0.f, 0.f};
#pragma unroll
    for (int j = 0; j < 4; ++j) {
      psa += hva[j];
      pqa = __builtin_elementwise_fma(hva[j], hva[j], pqa);
      psb += hvb[j];
      pqb = __builtin_elementwise_fma(hvb[j], hvb[j], pqb);
    }
    ln2[(0 * 8 + wv) * 64 + lane] = f32x2{psa.x + psa.y, pqa.x + pqa.y};
    ln2[(1 * 8 + wv) * 64 + lane] = f32x2{psb.x + psb.y, pqb.x + pqb.y};
  }
  __syncthreads();  // barrier B

  // ---- phase 2: LN finalize both; h_e0 -> B1, h_e1 -> B2
  {
    float sm0 = 0.f, sq0 = 0.f, sm1 = 0.f, sq1 = 0.f;
#pragma unroll
    for (int w = 0; w < 8; ++w) {
      f32x2 va = ln2[(0 * 8 + w) * 64 + lane];
      f32x2 vb = ln2[(1 * 8 + w) * 64 + lane];
      sm0 += va.x; sq0 += va.y;
      sm1 += vb.x; sq1 += vb.y;
    }
    float mu0 = sm0 * (1.f / 64.f);
    float rstd0 = rsqrtf(sq0 * (1.f / 64.f) - mu0 * mu0 + 1e-5f);
    float mu1 = sm1 * (1.f / 64.f);
    float rstd1 = rsqrtf(sq1 * (1.f / 64.f) - mu1 * mu1 + 1e-5f);
#pragma unroll
    for (int j = 0; j < 8; ++j) {
      int s = wv * 8 + j;
      float ha = (j & 1) ? hva[j >> 1].y : hva[j >> 1].x;
      float hb = (j & 1) ? hvb[j >> 1].y : hvb[j >> 1].x;
      float nv0 = (ha - mu0) * rstd0 * lnw[e0 * 64 + s] + lnb[e0 * 64 + s];
      float nv1 = (hb - mu1) * rstd1 * lnw[e1 * 64 + s] + lnb[e1 * 64 + s];
      B1[s * 72 + lane] = f2bf(nv0);
      B2[s * 72 + lane] = f2bf(nv1);
    }
  }
  __syncthreads();  // barrier C (ln2 reads done before B3 reused)

  float oacc[8];
#pragma unroll
  for (int i = 0; i < 8; ++i) oacc[i] = 0.f;

  // ---- phase 3: pw_in e0 (read B1) -> silu -> h3_e0 into B3
  {
    const unsigned short* wInE = wInBf + (size_t)e0 * 8192;
    short8 aA[2], aG[2];
#pragma unroll
    for (int kf = 0; kf < 2; ++kf) {
      aA[kf] = *(const short8*)(wInE + (16 * wi + r15) * 64 + kf * 32 + r4 * 8);
      aG[kf] = *(const short8*)(wInE + (64 + 16 * wi + r15) * 64 + kf * 32 + r4 * 8);
    }
    f32x4 accA[2], accG[2];
#pragma unroll
    for (int ntl = 0; ntl < 2; ++ntl)
#pragma unroll
      for (int v = 0; v < 4; ++v) {
        accA[ntl][v] = pwin_b[e0 * 128 + 16 * wi + r4 * 4 + v];
        accG[ntl][v] = pwin_b[e0 * 128 + 64 + 16 * wi + r4 * 4 + v];
      }
#pragma unroll
    for (int ntl = 0; ntl < 2; ++ntl) {
      const int nt = 2 * jh + ntl;
#pragma unroll
      for (int kf = 0; kf < 2; ++kf) {
        short8 bfr = *(const short8*)(B1 + (16 * nt + r15) * 72 + kf * 32 + r4 * 8);
        accA[ntl] = __builtin_amdgcn_mfma_f32_16x16x32_bf16(aA[kf], bfr, accA[ntl], 0, 0, 0);
        accG[ntl] = __builtin_amdgcn_mfma_f32_16x16x32_bf16(aG[kf], bfr, accG[ntl], 0, 0, 0);
      }
    }
#pragma unroll
    for (int ntl = 0; ntl < 2; ++ntl) {
      const int nt = 2 * jh + ntl;
      float hval[4];
#pragma unroll
      for (int v = 0; v < 4; ++v) {
        float a = accA[ntl][v];
        float g = accG[ntl][v];
        hval[v] = __fdividef(a, 1.f + __expf(-a)) * g;
      }
      uint2 w2;
      w2.x = (unsigned)f2bf(hval[0]) | ((unsigned)f2bf(hval[1]) << 16);
      w2.y = (unsigned)f2bf(hval[2]) | ((unsigned)f2bf(hval[3]) << 16);
      *(uint2*)(B3 + (16 * nt + r15) * 72 + 16 * wi + 4 * r4) = w2;
    }
  }
  __syncthreads();  // barrier D (h3_e0 ready; all B1 reads done)

  // ---- phase 4: pw_out e0 (read B3) -> oacc  ||  pw_in e1 (read B2) -> B1
  {
    const unsigned short* wOutE = wOutBf + (size_t)e0 * 4096;
    short8 aO[2];
#pragma unroll
    for (int kf = 0; kf < 2; ++kf)
      aO[kf] = *(const short8*)(wOutE + (16 * wi + r15) * 64 + kf * 32 + r4 * 8);
    f32x4 accO[2];
#pragma unroll
    for (int ntl = 0; ntl < 2; ++ntl)
#pragma unroll
      for (int v = 0; v < 4; ++v) accO[ntl][v] = 0.f;
#pragma unroll
    for (int ntl = 0; ntl < 2; ++ntl) {
      const int nt = 2 * jh + ntl;
#pragma unroll
      for (int kf = 0; kf < 2; ++kf) {
        short8 bfr = *(const short8*)(B3 + (16 * nt + r15) * 72 + kf * 32 + r4 * 8);
        accO[ntl] = __builtin_amdgcn_mfma_f32_16x16x32_bf16(aO[kf], bfr, accO[ntl], 0, 0, 0);
      }
    }
    float bO[4];
#pragma unroll
    for (int v = 0; v < 4; ++v) bO[v] = pwout_b[e0 * 64 + 16 * wi + r4 * 4 + v];
#pragma unroll
    for (int ntl = 0; ntl < 2; ++ntl)
#pragma unroll
      for (int v = 0; v < 4; ++v) oacc[ntl * 4 + v] += we0 * (accO[ntl][v] + bO[v]);

    // pw_in e1
    const unsigned short* wInE = wInBf + (size_t)e1 * 8192;
    short8 aA[2], aG[2];
#pragma unroll
    for (int kf = 0; kf < 2; ++kf) {
      aA[kf] = *(const short8*)(wInE + (16 * wi + r15) * 64 + kf * 32 + r4 * 8);
      aG[kf] = *(const short8*)(wInE + (64 + 16 * wi + r15) * 64 + kf * 32 + r4 * 8);
    }
    f32x4 accA[2], accG[2];
#pragma unroll
    for (int ntl = 0; ntl < 2; ++ntl)
#pragma unroll
      for (int v = 0; v < 4; ++v) {
        accA[ntl][v] = pwin_b[e1 * 128 + 16 * wi + r4 * 4 + v];
        accG[ntl][v] = pwin_b[e1 * 128 + 64 + 16 * wi + r4 * 4 + v];
      }
#pragma unroll
    for (int ntl = 0; ntl < 2; ++ntl) {
      const int nt = 2 * jh + ntl;
#pragma unroll
      for (int kf = 0; kf < 2; ++kf) {
        short8 bfr = *(const short8*)(B2 + (16 * nt + r15) * 72 + kf * 32 + r4 * 8);
        accA[ntl] = __builtin_amdgcn_mfma_f32_16x16x32_bf16(aA[kf], bfr, accA[ntl], 0, 0, 0);
        accG[ntl] = __builtin_amdgcn_mfma_f32_16x16x32_bf16(aG[kf], bfr, accG[ntl], 0, 0, 0);
      }
    }
#pragma unroll
    for (int ntl = 0; ntl < 2; ++ntl) {
      const int nt = 2 * jh + ntl;
      float hval[4];
#pragma unroll
      for (int v = 0; v < 4; ++v) {
        float a = accA[ntl][v];
        float g = accG[ntl][v];
        hval[v] = __fdividef(a, 1.f + __expf(-a)) * g;
      }
      uint2 w2;
      w2.x = (unsigned)f2bf(hval[0]) | ((unsigned)f2bf(hval[1]) << 16);
      w2.y = (unsigned)f2bf(hval[2]) | ((unsigned)f2bf(hval[3]) << 16);
      *(uint2*)(B1 + (16 * nt + r15) * 72 + 16 * wi + 4 * r4) = w2;  // h3_e1
    }
  }
  __syncthreads();  // barrier E (h3_e1 ready; B2/B3 reads done -> eb writable)

  // ---- phase 5: pw_out e1 (read B1) -> oacc; write eb (aliases B2+B3)
  {
    const unsigned short* wOutE = wOutBf + (size_t)e1 * 4096;
    short8 aO[2];
#pragma unroll
    for (int kf = 0; kf < 2; ++kf)
      aO[kf] = *(const short8*)(wOutE + (16 * wi + r15) * 64 + kf * 32 + r4 * 8);
    f32x4 accO[2];
#pragma unroll
    for (int ntl = 0; ntl < 2; ++ntl)
#pragma unroll
      for (int v = 0; v < 4; ++v) accO[ntl][v] = 0.f;
#pragma unroll
    for (int ntl = 0; ntl < 2; ++ntl) {
      const int nt = 2 * jh + ntl;
#pragma unroll
      for (int kf = 0; kf < 2; ++kf) {
        short8 bfr = *(const short8*)(B1 + (16 * nt + r15) * 72 + kf * 32 + r4 * 8);
        accO[ntl] = __builtin_amdgcn_mfma_f32_16x16x32_bf16(aO[kf], bfr, accO[ntl], 0, 0, 0);
      }
    }
    float bO[4];
#pragma unroll
    for (int v = 0; v < 4; ++v) bO[v] = pwout_b[e1 * 64 + 16 * wi + r4 * 4 + v];
#pragma unroll
    for (int ntl = 0; ntl < 2; ++ntl)
#pragma unroll
      for (int v = 0; v < 4; ++v) oacc[ntl * 4 + v] += we1 * (accO[ntl][v] + bO[v]);
  }
#pragma unroll
  for (int ntl = 0; ntl < 2; ++ntl)
#pragma unroll
    for (int v = 0; v < 4; ++v)
      eb[(16 * wi + 4 * r4 + v) * 68 + 16 * (2 * jh + ntl) + r15] = oacc[ntl * 4 + v];
  __syncthreads();  // barrier F

  // ---- epilogue: read eb, residual from global, store
#pragma unroll
  for (int it = 0; it < 2; ++it) {
    int g = it * 512 + t;
    int c = g >> 4, q = g & 15;
    float4 dv = *(const float4*)(eb + c * 68 + q * 4);
    float4 xv;   // residual from global (L2/L3-hot)
    if constexpr (REPACK)
      xv = ((const float4*)xr)[(size_t)bidx * 1024 + g];
    else
      xv = *(const float4*)(x + obase + (size_t)c * 131072 + (q >> 1) * 128 + (q & 1) * 4);
    float4 o4 = {xv.x + dv.x, xv.y + dv.y, xv.z + dv.z, xv.w + dv.w};
    *(float4*)(out + obase + (size_t)c * 131072 + (q >> 1) * 128 + (q & 1) * 4) = o4;
  }
}

extern "C" void kernel_launch(void* const* d_in, const int* in_sizes, int n_in,
                              void* d_out, int out_size, void* d_ws, size_t ws_size,
                              hipStream_t stream) {
  const float* x       = (const float*)d_in[0];
  const float* rw      = (const float*)d_in[1];
  const float* rb      = (const float*)d_in[2];
  const float* dww     = (const float*)d_in[3];
  const float* dwb     = (const float*)d_in[4];
  const float* lnw     = (const float*)d_in[5];
  const float* lnb     = (const float*)d_in[6];
  const float* pwin_w  = (const float*)d_in[7];
  const float* pwin_b  = (const float*)d_in[8];
  const float* pwout_w = (const float*)d_in[9];
  const float* pwout_b = (const float*)d_in[10];
  float* out = (float*)d_out;

  char* ws = (char*)d_ws;
  float*          partial_l = (float*)ws;
  unsigned short* dwTbf     = (unsigned short*)(ws + 1048576);
  int*            sel_i     = (int*)(ws + 1098752);
  float*          sel_w     = (float*)(ws + 1102848);
  unsigned short* wInBf     = (unsigned short*)(ws + 1106944);
  unsigned short* wOutBf    = (unsigned short*)(ws + 1238016);
  float*          xr        = (float*)(ws + 1303552);

  const bool repack = ws_size >= REPACK_NEED;

  hipLaunchKernelGGL(k_pre, dim3(482), dim3(256), 0, stream,
                     dww, pwin_w, pwout_w, dwTbf, wInBf, wOutBf);
  if (repack)
    hipLaunchKernelGGL(k_repack, dim3(2048), dim3(256), 0, stream, x, xr, partial_l);
  else
    hipLaunchKernelGGL(k_sum, dim3(512), dim3(256), 0, stream, x, partial_l);
  hipLaunchKernelGGL(k_router, dim3(512), dim3(64), 0, stream,
                     partial_l, rw, rb, sel_i, sel_w);
  if (repack)
    hipLaunchKernelGGL((k_main<true>), dim3(4096), dim3(512), 0, stream,
                       x, xr, dwTbf, dwb, lnw, lnb, pwin_b, pwout_b,
                       wInBf, wOutBf, sel_i, sel_w, out);
  else
    hipLaunchKernelGGL((k_main<false>), dim3(4096), dim3(512), 0, stream,
                       x, xr, dwTbf, dwb, lnw, lnb, pwin_b, pwout_b,
                       wInBf, wOutBf, sel_i, sel_w, out);
}